// Round 8
// baseline (430.756 us; speedup 1.0000x reference)
//
#include <hip/hip_runtime.h>
#include <hip/hip_bf16.h>

#define B_ 4
#define Q_ 1024
#define MEM_ 1024
#define D_ 1024
#define H_ 16
#define DH_ 64
#define KLEN_ 2048
#define NSPLIT 2

typedef __hip_bfloat16 bf16;
typedef __bf16 bf16x8 __attribute__((ext_vector_type(8)));
typedef float f32x4 __attribute__((ext_vector_type(4)));

__device__ __forceinline__ float bf2f(bf16 x) { return __bfloat162float(x); }
__device__ __forceinline__ bf16 f2bf(float x) { return __float2bfloat16(x); }

// 2^x via v_exp_f32 (NOT __exp2f: glibc math.h macro collision, R7 lesson)
__device__ __forceinline__ float ex2(float x) { return __builtin_amdgcn_exp2f(x); }

__device__ __forceinline__ unsigned short f2bf_bits(float x) {
  union { float f; unsigned u; } a; a.f = x;
  unsigned u = a.u;
  unsigned r = u + 0x7FFFu + ((u >> 16) & 1u);
  return (unsigned short)(r >> 16);
}

#define MFMA16(a, b, c) __builtin_amdgcn_mfma_f32_16x16x32_bf16((a), (b), (c), 0, 0, 0)
#define GLDS(gsrc, ldst) __builtin_amdgcn_global_load_lds( \
    (const __attribute__((address_space(1))) void*)(gsrc), \
    (__attribute__((address_space(3))) void*)(ldst), 16, 0, 0)

// swizzled LDS address for a 16B chunk: rows of 64 bf16 (128B = 8 chunks),
// chunk slot XORed with row&7 so column-slice b128 reads spread across banks
__device__ __forceinline__ int swz(int row, int ch) {
  return row * 64 + ((ch ^ (row & 7)) * 8);
}

// 0.125 (1/sqrt(DH)) * log2(e): scores land in log2 domain -> exp2 softmax
#define QSCALE 0.180336880111112f

// ---------------- conversions ----------------
struct CvtArgs { const float* src[3]; bf16* dst[3]; int n4[3]; };

__global__ void cvt_kernel(CvtArgs a) {
  const int z = blockIdx.z;
  const float4* s = (const float4*)a.src[z];
  const int n4 = a.n4[z];
  const int i = blockIdx.x * blockDim.x + threadIdx.x;
  if (i < n4) {
    float4 v = s[i];
    ushort4 o;
    o.x = f2bf_bits(v.x); o.y = f2bf_bits(v.y);
    o.z = f2bf_bits(v.z); o.w = f2bf_bits(v.w);
    ((ushort4*)a.dst[z])[i] = o;
  }
}

// ---------------- weight transpose (f32 -> bf16, Wt[n][k] = W[k][n]) -------
struct TpArgs { const float* w[5]; bf16* o[5]; };

__global__ void tp_kernel(TpArgs a) {
  __shared__ float t[32][33];
  const int z = blockIdx.z;
  const float* W = a.w[z];
  bf16* Wt = a.o[z];
  const int bx = blockIdx.x * 32, by = blockIdx.y * 32;
  const int tx = threadIdx.x, ty = threadIdx.y;
#pragma unroll
  for (int y = ty; y < 32; y += 8) t[y][tx] = W[(long)(by + y) * D_ + bx + tx];
  __syncthreads();
#pragma unroll
  for (int y = ty; y < 32; y += 8)
    Wt[(long)(bx + y) * D_ + by + tx] = f2bf(t[tx][y]);
}

// ---------------- GEMM (A row-major MxK bf16, Bt row-major NxK bf16) -------
enum { EPI_HQKV = 0, EPI_MEMKV, EPI_R, EPI_OUT };

struct GemmArgs {
  const bf16* A; const bf16* Bt;
  int K;
  long batchA, batchB;
  bf16 *qw, *qr, *kall, *vT, *rhead;
  float *kcache, *vcache, *fout;
  const float *rwb, *rrb;
};

template <int MODE>
__global__ __launch_bounds__(256) void gemm_bt(GemmArgs g) {
  __shared__ bf16 As[128 * 32];
  __shared__ bf16 Bs[128 * 32];
  const int tid = threadIdx.x;
  const int wid = tid >> 6, lane = tid & 63;
  const int wr = wid >> 1, wc = wid & 1;
  const int lo = lane & 15, lg = lane >> 4;
  const int m0 = blockIdx.y * 128, n0 = blockIdx.x * 128;
  const int K = g.K;
  const bf16* A = g.A + (long)blockIdx.z * g.batchA;
  const bf16* Bt = g.Bt + (long)blockIdx.z * g.batchB;

  f32x4 acc[4][4] = {};

  const int srow = 32 * wid + (lane >> 2);
  const int scol = (lane & 3) * 8;
  const bf16* asrc = A + (long)(m0 + srow) * K + scol;
  const bf16* bsrc = Bt + (long)(n0 + srow) * K + scol;
  bf16* adst0 = &As[(32 * wid) * 32];
  bf16* adst1 = &As[(32 * wid + 16) * 32];
  bf16* bdst0 = &Bs[(32 * wid) * 32];
  bf16* bdst1 = &Bs[(32 * wid + 16) * 32];

  for (int kt = 0; kt < K; kt += 32) {
    GLDS(asrc, adst0);
    GLDS(asrc + 16 * (long)K, adst1);
    GLDS(bsrc, bdst0);
    GLDS(bsrc + 16 * (long)K, bdst1);
    asrc += 32; bsrc += 32;
    __syncthreads();
    bf16x8 af[4], bfv[4];
#pragma unroll
    for (int m = 0; m < 4; ++m)
      af[m] = *(const bf16x8*)&As[(64 * wr + 16 * m + lo) * 32 + lg * 8];
#pragma unroll
    for (int n = 0; n < 4; ++n)
      bfv[n] = *(const bf16x8*)&Bs[(64 * wc + 16 * n + lo) * 32 + lg * 8];
#pragma unroll
    for (int m = 0; m < 4; ++m)
#pragma unroll
      for (int n = 0; n < 4; ++n)
        acc[m][n] = MFMA16(af[m], bfv[n], acc[m][n]);
    __syncthreads();
  }

#pragma unroll
  for (int m = 0; m < 4; ++m) {
#pragma unroll
    for (int n = 0; n < 4; ++n) {
#pragma unroll
      for (int r = 0; r < 4; ++r) {
        const float v = acc[m][n][r];
        const int gr = m0 + 64 * wr + 16 * m + lg * 4 + r;
        const int gc = n0 + 64 * wc + 16 * n + lo;
        if constexpr (MODE == EPI_HQKV) {
          const int b = gr >> 10, i = gr & 1023;
          const int seg = gc >> 10, c = gc & 1023;
          const int hh = c >> 6, dh = c & 63;
          const long bh = (long)(b * H_ + hh);
          if (seg == 0) {
            // fold 1/sqrt(DH) * log2(e) into q: scores in log2 domain
            const long idx = (bh * Q_ + i) * DH_ + dh;
            g.qw[idx] = f2bf((v + g.rwb[c]) * QSCALE);
            g.qr[idx] = f2bf((v + g.rrb[c]) * QSCALE);
          } else if (seg == 1) {
            g.kall[(bh * KLEN_ + MEM_ + i) * DH_ + dh] = f2bf(v);
            g.kcache[(bh * MEM_ + i) * DH_ + dh] = v;
          } else {
            g.vT[(bh * DH_ + dh) * KLEN_ + MEM_ + i] = f2bf(v);
            g.vcache[(bh * MEM_ + i) * DH_ + dh] = v;
          }
        } else if constexpr (MODE == EPI_MEMKV) {
          const int b = gr >> 10, i = gr & 1023;
          const int seg = gc >> 10, c = gc & 1023;
          const int hh = c >> 6, dh = c & 63;
          const long bh = (long)(b * H_ + hh);
          if (seg == 0) g.kall[(bh * KLEN_ + i) * DH_ + dh] = f2bf(v);
          else          g.vT[(bh * DH_ + dh) * KLEN_ + i] = f2bf(v);
        } else if constexpr (MODE == EPI_R) {
          const int hh = gc >> 6, dh = gc & 63;
          g.rhead[((long)hh * KLEN_ + gr) * DH_ + dh] = f2bf(v);
        } else {  // EPI_OUT
          g.fout[(long)gr * D_ + gc] = v;
        }
      }
    }
  }
}

// ---------------- fused attention, LDS-staged shared K/V/rhead -------------
// 1D grid of 2048 hw blocks; L = ((hw&7)<<8)|(hw>>3) keeps the 16 x-blocks of
// one (b,h,js) on one XCD. Per j-iter: K/V staged once; rhead delta-band kept
// in a 128-row CIRCULAR buffer (band shifts by 64/iter -> stage only 64 new
// rows). Softmax in log2 domain (exp2), defer-max gate (T13), setprio (T5).
__global__ __launch_bounds__(256) void attn_kernel(
    const bf16* __restrict__ qw, const bf16* __restrict__ qr,
    const bf16* __restrict__ kall, const bf16* __restrict__ vT,
    const bf16* __restrict__ rhead, float* __restrict__ po,
    float2* __restrict__ pml) {
  __shared__ bf16 Kt[64 * 64];
  __shared__ bf16 Vt[64 * 64];
  __shared__ bf16 Rt[128 * 64];
  __shared__ bf16 Ps[4][16][72];
  __shared__ bf16 Sd[4][16][83];
  const int hw = blockIdx.x;
  const int L = ((hw & 7) << 8) | (hw >> 3);
  const int xb = L & 15;
  const int h = (L >> 4) & 15;
  const int js = (L >> 8) & 1;
  const int b = L >> 9;
  const int tid = threadIdx.x;
  const int wid = tid >> 6, lane = tid & 63;
  const int lo = lane & 15, lg = lane >> 4;
  const int I0 = xb * 64;
  const int i0 = I0 + wid * 16;
  const long bh = (long)(b * H_ + h);
  const bf16* rh = rhead + (long)h * KLEN_ * DH_;
  const bf16* kbase = kall + bh * KLEN_ * DH_;
  const bf16* vbase = vT + bh * DH_ * KLEN_;

  const bf16x8 aq0 = *(const bf16x8*)&qw[(bh * Q_ + i0 + lo) * DH_ + lg * 8];
  const bf16x8 aq1 = *(const bf16x8*)&qw[(bh * Q_ + i0 + lo) * DH_ + 32 + lg * 8];
  const bf16x8 ar0 = *(const bf16x8*)&qr[(bh * Q_ + i0 + lo) * DH_ + lg * 8];
  const bf16x8 ar1 = *(const bf16x8*)&qr[(bh * Q_ + i0 + lo) * DH_ + 32 + lg * 8];

  f32x4 o[4] = {};
  float mrun[4], lrun[4];
#pragma unroll
  for (int r = 0; r < 4; ++r) { mrun[r] = -1e30f; lrun[r] = 0.f; }

  const int jbeg = js << 10;
  const int base0 = jbeg - I0 - 63;  // delta of Rt slot 0 (iter 0 band low)

  // Prologue: stage the full 128-row delta band (slots 0..127)
#pragma unroll
  for (int s = 0; s < 4; ++s) {
    const int c = tid + s * 256;
    const int row = c >> 3;
    const int dcol = base0 + row;
    int m = dcol + ((dcol >= 1026) ? -1026 : 1023);
    m = max(0, min(m, KLEN_ - 1));
    const int gch = (c & 7) ^ (row & 7);
    GLDS(rh + (long)m * DH_ + gch * 8, &Rt[c * 8]);
  }

  for (int k = 0; k < KLEN_ / NSPLIT / 64; ++k) {
    const int j0 = jbeg + 64 * k;
    // ---- STAGE: K (2 chunks/thread), V (2), new 64 rhead rows (2, k>0) ----
#pragma unroll
    for (int s = 0; s < 2; ++s) {
      const int c = tid + s * 256;
      const int row = c >> 3;
      const int gch = (c & 7) ^ (row & 7);
      GLDS(kbase + (long)(j0 + row) * DH_ + gch * 8, &Kt[c * 8]);
    }
#pragma unroll
    for (int s = 0; s < 2; ++s) {
      const int c = tid + s * 256;
      const int row = c >> 3;
      const int gch = (c & 7) ^ (row & 7);
      GLDS(vbase + (long)row * KLEN_ + j0 + gch * 8, &Vt[c * 8]);
    }
    if (k > 0) {
      const int slot_base = ((k + 1) & 1) << 6;
      const int d_start = base0 + 64 * k + 64;
#pragma unroll
      for (int s = 0; s < 2; ++s) {
        const int c = tid + s * 256;
        const int row = c >> 3;  // 0..63
        const int dcol = d_start + row;
        int m = dcol + ((dcol >= 1026) ? -1026 : 1023);
        m = max(0, min(m, KLEN_ - 1));
        const int gch = (c & 7) ^ (row & 7);
        GLDS(rh + (long)m * DH_ + gch * 8, &Rt[(slot_base + row) * 64 + gch * 8]);
      }
    }
    __syncthreads();  // staged tiles visible to all waves

    // ---- ac = qw . K^T (from LDS) ----
    f32x4 s[4];
    __builtin_amdgcn_s_setprio(1);
#pragma unroll
    for (int t = 0; t < 4; ++t) {
      const bf16x8 kb0 = *(const bf16x8*)&Kt[swz(16 * t + lo, lg)];
      const bf16x8 kb1 = *(const bf16x8*)&Kt[swz(16 * t + lo, lg + 4)];
      f32x4 z = {};
      z = MFMA16(aq0, kb0, z);
      z = MFMA16(aq1, kb1, z);
      s[t] = z;
    }
    __builtin_amdgcn_s_setprio(0);
    // ---- bd band in delta-space (from circular Rt) ----
    const int dbase = j0 - i0 - 15;
    const int cbase = ((k & 1) << 6) + 48 - 16 * wid;
    __builtin_amdgcn_s_setprio(1);
#pragma unroll
    for (int t = 0; t < 5; ++t) {
      const int dmin = dbase + 16 * t;
      const bool need1 = (dmin <= 1024);
      const bool need2 = (dmin + 15 >= 1026);
      const int dcol = dmin + lo;
      const int c = (cbase + 16 * t + lo) & 127;  // circular Rt slot
      const bf16x8 rb0 = *(const bf16x8*)&Rt[swz(c, lg)];
      const bf16x8 rb1 = *(const bf16x8*)&Rt[swz(c, lg + 4)];
      f32x4 z1 = {}, z2 = {};
      if (need1) { z1 = MFMA16(ar0, rb0, z1); z1 = MFMA16(ar1, rb1, z1); }
      if (need2) {
        const int rs = min(i0 + 1 + lo, Q_ - 1);
        const bf16x8 as0 = *(const bf16x8*)&qr[(bh * Q_ + rs) * DH_ + lg * 8];
        const bf16x8 as1 = *(const bf16x8*)&qr[(bh * Q_ + rs) * DH_ + 32 + lg * 8];
        z2 = MFMA16(as0, rb0, z2);
        z2 = MFMA16(as1, rb1, z2);
      }
#pragma unroll
      for (int r = 0; r < 4; ++r) {
        float v = (dcol >= 1026) ? z2[r] : z1[r];
        if (dcol == 1025) v = 0.f;
        Sd[wid][lg * 4 + r][16 * t + lo] = f2bf(v);
      }
    }
    __builtin_amdgcn_s_setprio(0);
    // ---- softmax (online, log2 domain, defer-max) ----
    float mnew[4];
    int ok = 1;
#pragma unroll
    for (int r = 0; r < 4; ++r) {
      const int row = lg * 4 + r;
      float mt = -1e30f;
#pragma unroll
      for (int t = 0; t < 4; ++t) {
        const float bd = bf2f(Sd[wid][row][16 * t + lo + 15 - row]);
        const float sc = s[t][r] + bd;
        s[t][r] = sc;
        mt = fmaxf(mt, sc);
      }
#pragma unroll
      for (int d = 1; d < 16; d <<= 1) mt = fmaxf(mt, __shfl_xor(mt, d));
      mnew[r] = fmaxf(mrun[r], mt);
      ok &= (mt <= mrun[r] + 8.0f);
    }
    if (__all(ok)) {
      // defer: keep old max, P bounded by 2^8 (bf16-safe); skip o-rescale
#pragma unroll
      for (int r = 0; r < 4; ++r) {
        float rsum = 0.f;
#pragma unroll
        for (int t = 0; t < 4; ++t) {
          const float p = ex2(s[t][r] - mrun[r]);
          s[t][r] = p;
          rsum += p;
        }
#pragma unroll
        for (int d = 1; d < 16; d <<= 1) rsum += __shfl_xor(rsum, d);
        lrun[r] += rsum;
      }
    } else {
#pragma unroll
      for (int r = 0; r < 4; ++r) {
        float rsum = 0.f;
#pragma unroll
        for (int t = 0; t < 4; ++t) {
          const float p = ex2(s[t][r] - mnew[r]);
          s[t][r] = p;
          rsum += p;
        }
#pragma unroll
        for (int d = 1; d < 16; d <<= 1) rsum += __shfl_xor(rsum, d);
        const float scale = ex2(mrun[r] - mnew[r]);
        lrun[r] = lrun[r] * scale + rsum;
        mrun[r] = mnew[r];
#pragma unroll
        for (int u = 0; u < 4; ++u) o[u][r] *= scale;
      }
    }
    // ---- P -> LDS -> A-frag, PV (V from LDS) ----
#pragma unroll
    for (int t = 0; t < 4; ++t)
#pragma unroll
      for (int r = 0; r < 4; ++r)
        Ps[wid][lg * 4 + r][16 * t + lo] = f2bf(s[t][r]);
    const bf16x8 pa0 = *(const bf16x8*)&Ps[wid][lo][lg * 8];
    const bf16x8 pa1 = *(const bf16x8*)&Ps[wid][lo][32 + lg * 8];
    __builtin_amdgcn_s_setprio(1);
#pragma unroll
    for (int u = 0; u < 4; ++u) {
      const bf16x8 vb0 = *(const bf16x8*)&Vt[swz(16 * u + lo, lg)];
      const bf16x8 vb1 = *(const bf16x8*)&Vt[swz(16 * u + lo, lg + 4)];
      o[u] = MFMA16(pa0, vb0, o[u]);
      o[u] = MFMA16(pa1, vb1, o[u]);
    }
    __builtin_amdgcn_s_setprio(0);
    __syncthreads();  // protect Kt/Vt/Rt before next stage overwrites
  }
  // ---- partial outputs ----
#pragma unroll
  for (int u = 0; u < 4; ++u) {
#pragma unroll
    for (int r = 0; r < 4; ++r) {
      const int i = i0 + lg * 4 + r;
      po[(((long)(bh * Q_ + i)) * NSPLIT + js) * DH_ + 16 * u + lo] = o[u][r];
    }
  }
  if (lo == 0) {
#pragma unroll
    for (int r = 0; r < 4; ++r) {
      const int i = i0 + lg * 4 + r;
      pml[((long)(bh * Q_ + i)) * NSPLIT + js] = make_float2(mrun[r], lrun[r]);
    }
  }
}

// ---------------- combine partial softmax halves (log2 domain) -------------
__global__ __launch_bounds__(256) void combine_kernel(
    const float* __restrict__ po, const float2* __restrict__ pml,
    bf16* __restrict__ attnv) {
  const long gid = (long)blockIdx.x * 256 + threadIdx.x;  // B*H*Q*DH
  const int col = gid & 63;
  const long row = gid >> 6;  // bh*Q + i
  const float2 ml0 = pml[row * NSPLIT];
  const float2 ml1 = pml[row * NSPLIT + 1];
  const float m = fmaxf(ml0.x, ml1.x);
  const float w0 = ex2(ml0.x - m), w1 = ex2(ml1.x - m);
  const float num = po[(row * NSPLIT) * DH_ + col] * w0 +
                    po[(row * NSPLIT + 1) * DH_ + col] * w1;
  const float den = ml0.y * w0 + ml1.y * w1;
  const int b = (int)(row >> 14);
  const int h = (int)(row >> 10) & 15;
  const int i = (int)row & 1023;
  attnv[((long)(b * Q_ + i)) * D_ + h * DH_ + col] = f2bf(num / den);
}

// ---------------- host ----------------
extern "C" void kernel_launch(void* const* d_in, const int* in_sizes, int n_in,
                              void* d_out, int out_size, void* d_ws, size_t ws_size,
                              hipStream_t stream) {
  (void)in_sizes; (void)n_in; (void)out_size; (void)ws_size;
  const float* h_in  = (const float*)d_in[0];
  const float* mem_in= (const float*)d_in[1];
  const float* r_in  = (const float*)d_in[2];
  const float* Wq = (const float*)d_in[3];
  const float* Wk = (const float*)d_in[4];
  const float* Wv = (const float*)d_in[5];
  const float* Wr = (const float*)d_in[6];
  const float* Wo = (const float*)d_in[7];
  const float* rwb = (const float*)d_in[8];
  const float* rrb = (const float*)d_in[9];

  float* out = (float*)d_out;
  float* kcache = out + (long)B_ * Q_ * D_;
  float* vcache = kcache + (long)B_ * H_ * MEM_ * DH_;

  char* w = (char*)d_ws;
  auto alloc = [&](size_t bytes) {
    char* p = w;
    w += (bytes + 255) & ~(size_t)255;
    return p;
  };
  bf16* h_bf   = (bf16*)alloc((size_t)B_ * Q_ * D_ * 2);
  bf16* mem_bf = (bf16*)alloc((size_t)B_ * MEM_ * D_ * 2);
  bf16* r_bf   = (bf16*)alloc((size_t)KLEN_ * D_ * 2);
  bf16* Wqt = (bf16*)alloc((size_t)D_ * D_ * 2);
  bf16* Wkt = (bf16*)alloc((size_t)D_ * D_ * 2);
  bf16* Wvt = (bf16*)alloc((size_t)D_ * D_ * 2);
  bf16* Wrt = (bf16*)alloc((size_t)D_ * D_ * 2);
  bf16* Wot = (bf16*)alloc((size_t)D_ * D_ * 2);
  bf16* qw    = (bf16*)alloc((size_t)B_ * H_ * Q_ * DH_ * 2);
  bf16* qr    = (bf16*)alloc((size_t)B_ * H_ * Q_ * DH_ * 2);
  bf16* kall  = (bf16*)alloc((size_t)B_ * H_ * KLEN_ * DH_ * 2);
  bf16* vT    = (bf16*)alloc((size_t)B_ * H_ * KLEN_ * DH_ * 2);
  bf16* rhead = (bf16*)alloc((size_t)H_ * KLEN_ * DH_ * 2);
  bf16* attnv = (bf16*)alloc((size_t)B_ * Q_ * D_ * 2);
  float* po   = (float*)alloc((size_t)B_ * H_ * Q_ * NSPLIT * DH_ * 4);
  float2* pml = (float2*)alloc((size_t)B_ * H_ * Q_ * NSPLIT * 8);

  // 1. f32 -> bf16 conversions
  CvtArgs ca;
  ca.src[0] = h_in;   ca.dst[0] = h_bf;   ca.n4[0] = B_ * Q_ * D_ / 4;
  ca.src[1] = mem_in; ca.dst[1] = mem_bf; ca.n4[1] = B_ * MEM_ * D_ / 4;
  ca.src[2] = r_in;   ca.dst[2] = r_bf;   ca.n4[2] = KLEN_ * D_ / 4;
  cvt_kernel<<<dim3((B_ * Q_ * D_ / 4 + 255) / 256, 1, 3), 256, 0, stream>>>(ca);

  // 2. weight transposes
  TpArgs ta;
  ta.w[0] = Wq; ta.o[0] = Wqt;
  ta.w[1] = Wk; ta.o[1] = Wkt;
  ta.w[2] = Wv; ta.o[2] = Wvt;
  ta.w[3] = Wr; ta.o[3] = Wrt;
  ta.w[4] = Wo; ta.o[4] = Wot;
  tp_kernel<<<dim3(32, 32, 5), dim3(32, 8), 0, stream>>>(ta);

  GemmArgs g{};
  g.qw = qw; g.qr = qr; g.kall = kall; g.vT = vT; g.rhead = rhead;
  g.kcache = kcache; g.vcache = vcache; g.fout = out; g.rwb = rwb; g.rrb = rrb;

  // 3. h @ [Wq|Wk|Wv]  (M=4096, N=3072, K=1024)
  g.A = h_bf; g.Bt = Wqt; g.K = D_; g.batchA = 0; g.batchB = 0;
  gemm_bt<EPI_HQKV><<<dim3(3 * D_ / 128, B_ * Q_ / 128, 1), 256, 0, stream>>>(g);

  // 4. mem @ [Wk|Wv]  (M=4096, N=2048, K=1024)
  g.A = mem_bf; g.Bt = Wkt;
  gemm_bt<EPI_MEMKV><<<dim3(2 * D_ / 128, B_ * MEM_ / 128, 1), 256, 0, stream>>>(g);

  // 5. r @ Wr  (M=2048, N=1024, K=1024)
  g.A = r_bf; g.Bt = Wrt;
  gemm_bt<EPI_R><<<dim3(D_ / 128, KLEN_ / 128, 1), 256, 0, stream>>>(g);

  // 6. fused attention (KV-split, XCD-swizzled, LDS-staged) + combine
  attn_kernel<<<dim3(Q_ / 64 * H_ * B_ * NSPLIT), 256, 0, stream>>>(
      qw, qr, kall, vT, rhead, po, pml);
  combine_kernel<<<dim3(B_ * H_ * Q_ * DH_ / 256), 256, 0, stream>>>(po, pml, attnv);

  // 7. out = attnv @ Wo  (M=4096, N=1024, K=1024)
  g.A = attnv; g.Bt = Wot; g.K = D_; g.batchA = 0; g.batchB = 0;
  gemm_bt<EPI_OUT><<<dim3(D_ / 128, B_ * Q_ / 128, 1), 256, 0, stream>>>(g);
}

// Round 9
// 423.388 us; speedup vs baseline: 1.0174x; 1.0174x over previous
//
#include <hip/hip_runtime.h>
#include <hip/hip_bf16.h>

#define B_ 4
#define Q_ 1024
#define MEM_ 1024
#define D_ 1024
#define H_ 16
#define DH_ 64
#define KLEN_ 2048
#define NSPLIT 2

typedef __hip_bfloat16 bf16;
typedef __bf16 bf16x8 __attribute__((ext_vector_type(8)));
typedef float f32x4 __attribute__((ext_vector_type(4)));

__device__ __forceinline__ float bf2f(bf16 x) { return __bfloat162float(x); }
__device__ __forceinline__ bf16 f2bf(float x) { return __float2bfloat16(x); }

// 2^x via v_exp_f32 (NOT __exp2f: glibc math.h macro collision, R7 lesson)
__device__ __forceinline__ float ex2(float x) { return __builtin_amdgcn_exp2f(x); }

__device__ __forceinline__ unsigned short f2bf_bits(float x) {
  union { float f; unsigned u; } a; a.f = x;
  unsigned u = a.u;
  unsigned r = u + 0x7FFFu + ((u >> 16) & 1u);
  return (unsigned short)(r >> 16);
}

#define MFMA16(a, b, c) __builtin_amdgcn_mfma_f32_16x16x32_bf16((a), (b), (c), 0, 0, 0)
#define GLDS(gsrc, ldst) __builtin_amdgcn_global_load_lds( \
    (const __attribute__((address_space(1))) void*)(gsrc), \
    (__attribute__((address_space(3))) void*)(ldst), 16, 0, 0)

// swizzled LDS address for a 16B chunk: rows of 64 bf16 (128B = 8 chunks),
// chunk slot XORed with row&7 so column-slice b128 reads spread across banks
__device__ __forceinline__ int swz(int row, int ch) {
  return row * 64 + ((ch ^ (row & 7)) * 8);
}

// 0.125 (1/sqrt(DH)) * log2(e): scores land in log2 domain -> exp2 softmax
#define QSCALE 0.180336880111112f

// ---------------- conversions ----------------
struct CvtArgs { const float* src[3]; bf16* dst[3]; int n4[3]; };

__global__ void cvt_kernel(CvtArgs a) {
  const int z = blockIdx.z;
  const float4* s = (const float4*)a.src[z];
  const int n4 = a.n4[z];
  const int i = blockIdx.x * blockDim.x + threadIdx.x;
  if (i < n4) {
    float4 v = s[i];
    ushort4 o;
    o.x = f2bf_bits(v.x); o.y = f2bf_bits(v.y);
    o.z = f2bf_bits(v.z); o.w = f2bf_bits(v.w);
    ((ushort4*)a.dst[z])[i] = o;
  }
}

// ---------------- weight transpose (f32 -> bf16, Wt[n][k] = W[k][n]) -------
struct TpArgs { const float* w[5]; bf16* o[5]; };

__global__ void tp_kernel(TpArgs a) {
  __shared__ float t[32][33];
  const int z = blockIdx.z;
  const float* W = a.w[z];
  bf16* Wt = a.o[z];
  const int bx = blockIdx.x * 32, by = blockIdx.y * 32;
  const int tx = threadIdx.x, ty = threadIdx.y;
#pragma unroll
  for (int y = ty; y < 32; y += 8) t[y][tx] = W[(long)(by + y) * D_ + bx + tx];
  __syncthreads();
#pragma unroll
  for (int y = ty; y < 32; y += 8)
    Wt[(long)(bx + y) * D_ + by + tx] = f2bf(t[tx][y]);
}

// ---------------- GEMM (A row-major MxK bf16, Bt row-major NxK bf16) -------
enum { EPI_HQKV = 0, EPI_MEMKV, EPI_R, EPI_OUT };

struct GemmArgs {
  const bf16* A; const bf16* Bt;
  int K;
  long batchA, batchB;
  bf16 *qw, *qr, *kall, *vT, *rhead;
  float *kcache, *vcache, *fout;
  const float *rwb, *rrb;
};

template <int MODE>
__global__ __launch_bounds__(256) void gemm_bt(GemmArgs g) {
  __shared__ bf16 As[128 * 32];
  __shared__ bf16 Bs[128 * 32];
  const int tid = threadIdx.x;
  const int wid = tid >> 6, lane = tid & 63;
  const int wr = wid >> 1, wc = wid & 1;
  const int lo = lane & 15, lg = lane >> 4;
  const int m0 = blockIdx.y * 128, n0 = blockIdx.x * 128;
  const int K = g.K;
  const bf16* A = g.A + (long)blockIdx.z * g.batchA;
  const bf16* Bt = g.Bt + (long)blockIdx.z * g.batchB;

  f32x4 acc[4][4] = {};

  const int srow = 32 * wid + (lane >> 2);
  const int scol = (lane & 3) * 8;
  const bf16* asrc = A + (long)(m0 + srow) * K + scol;
  const bf16* bsrc = Bt + (long)(n0 + srow) * K + scol;
  bf16* adst0 = &As[(32 * wid) * 32];
  bf16* adst1 = &As[(32 * wid + 16) * 32];
  bf16* bdst0 = &Bs[(32 * wid) * 32];
  bf16* bdst1 = &Bs[(32 * wid + 16) * 32];

  for (int kt = 0; kt < K; kt += 32) {
    GLDS(asrc, adst0);
    GLDS(asrc + 16 * (long)K, adst1);
    GLDS(bsrc, bdst0);
    GLDS(bsrc + 16 * (long)K, bdst1);
    asrc += 32; bsrc += 32;
    __syncthreads();
    bf16x8 af[4], bfv[4];
#pragma unroll
    for (int m = 0; m < 4; ++m)
      af[m] = *(const bf16x8*)&As[(64 * wr + 16 * m + lo) * 32 + lg * 8];
#pragma unroll
    for (int n = 0; n < 4; ++n)
      bfv[n] = *(const bf16x8*)&Bs[(64 * wc + 16 * n + lo) * 32 + lg * 8];
#pragma unroll
    for (int m = 0; m < 4; ++m)
#pragma unroll
      for (int n = 0; n < 4; ++n)
        acc[m][n] = MFMA16(af[m], bfv[n], acc[m][n]);
    __syncthreads();
  }

#pragma unroll
  for (int m = 0; m < 4; ++m) {
#pragma unroll
    for (int n = 0; n < 4; ++n) {
#pragma unroll
      for (int r = 0; r < 4; ++r) {
        const float v = acc[m][n][r];
        const int gr = m0 + 64 * wr + 16 * m + lg * 4 + r;
        const int gc = n0 + 64 * wc + 16 * n + lo;
        if constexpr (MODE == EPI_HQKV) {
          const int b = gr >> 10, i = gr & 1023;
          const int seg = gc >> 10, c = gc & 1023;
          const int hh = c >> 6, dh = c & 63;
          const long bh = (long)(b * H_ + hh);
          if (seg == 0) {
            // fold 1/sqrt(DH) * log2(e) into q: scores in log2 domain
            const long idx = (bh * Q_ + i) * DH_ + dh;
            g.qw[idx] = f2bf((v + g.rwb[c]) * QSCALE);
            g.qr[idx] = f2bf((v + g.rrb[c]) * QSCALE);
          } else if (seg == 1) {
            g.kall[(bh * KLEN_ + MEM_ + i) * DH_ + dh] = f2bf(v);
            g.kcache[(bh * MEM_ + i) * DH_ + dh] = v;
          } else {
            g.vT[(bh * DH_ + dh) * KLEN_ + MEM_ + i] = f2bf(v);
            g.vcache[(bh * MEM_ + i) * DH_ + dh] = v;
          }
        } else if constexpr (MODE == EPI_MEMKV) {
          const int b = gr >> 10, i = gr & 1023;
          const int seg = gc >> 10, c = gc & 1023;
          const int hh = c >> 6, dh = c & 63;
          const long bh = (long)(b * H_ + hh);
          if (seg == 0) g.kall[(bh * KLEN_ + i) * DH_ + dh] = f2bf(v);
          else          g.vT[(bh * DH_ + dh) * KLEN_ + i] = f2bf(v);
        } else if constexpr (MODE == EPI_R) {
          const int hh = gc >> 6, dh = gc & 63;
          g.rhead[((long)hh * KLEN_ + gr) * DH_ + dh] = f2bf(v);
        } else {  // EPI_OUT
          g.fout[(long)gr * D_ + gc] = v;
        }
      }
    }
  }
}

// ---------------- fused attention: pipelined LDS staging -------------------
// 1D grid of 2048 hw blocks; L = ((hw&7)<<8)|(hw>>3) keeps the 16 x-blocks of
// one (b,h,js) on one XCD. T3 minimum-2-phase pipeline: per iter, STAGE(next)
// into the other K/V buffer + the free rhead half-band, THEN compute(cur),
// THEN one __syncthreads() (drains vmcnt -> next tiles visible; protects
// buffers). Staging latency hides under compute; 1 barrier/iter (was 2).
// rhead delta-band = 3 rotating 64-row halves: compute(k) reads halves
// {k, k+1}; staging writes half k+2 (never read concurrently).
__global__ __launch_bounds__(256) void attn_kernel(
    const bf16* __restrict__ qw, const bf16* __restrict__ qr,
    const bf16* __restrict__ kall, const bf16* __restrict__ vT,
    const bf16* __restrict__ rhead, float* __restrict__ po,
    float2* __restrict__ pml) {
  __shared__ bf16 Kt[2][64 * 64];
  __shared__ bf16 Vt[2][64 * 64];
  __shared__ bf16 Rb[3][64 * 64];
  __shared__ bf16 Ps[4][16][72];
  __shared__ bf16 Sd[4][16][83];
  const int hw = blockIdx.x;
  const int L = ((hw & 7) << 8) | (hw >> 3);
  const int xb = L & 15;
  const int h = (L >> 4) & 15;
  const int js = (L >> 8) & 1;
  const int b = L >> 9;
  const int tid = threadIdx.x;
  const int wid = tid >> 6, lane = tid & 63;
  const int lo = lane & 15, lg = lane >> 4;
  const int I0 = xb * 64;
  const int i0 = I0 + wid * 16;
  const long bh = (long)(b * H_ + h);
  const bf16* rh = rhead + (long)h * KLEN_ * DH_;
  const bf16* kbase = kall + bh * KLEN_ * DH_;
  const bf16* vbase = vT + bh * DH_ * KLEN_;

  const bf16x8 aq0 = *(const bf16x8*)&qw[(bh * Q_ + i0 + lo) * DH_ + lg * 8];
  const bf16x8 aq1 = *(const bf16x8*)&qw[(bh * Q_ + i0 + lo) * DH_ + 32 + lg * 8];
  const bf16x8 ar0 = *(const bf16x8*)&qr[(bh * Q_ + i0 + lo) * DH_ + lg * 8];
  const bf16x8 ar1 = *(const bf16x8*)&qr[(bh * Q_ + i0 + lo) * DH_ + 32 + lg * 8];

  f32x4 o[4] = {};
  float mrun[4], lrun[4];
#pragma unroll
  for (int r = 0; r < 4; ++r) { mrun[r] = -1e30f; lrun[r] = 0.f; }

  const int jbeg = js << 10;
  const int base0 = jbeg - I0 - 63;  // delta of half-band 0, row 0
  const int NITER = KLEN_ / NSPLIT / 64;

  // staging lane geometry (same for K/V/R: 64 rows x 8 chunks, 2 per thread)
  const int c0 = tid, c1 = tid + 256;
  const int row0 = c0 >> 3, row1 = c1 >> 3;
  const int gch0 = (c0 & 7) ^ (row0 & 7), gch1 = (c1 & 7) ^ (row1 & 7);

  // rhead half-band m: delta in [base0+64m, base0+64m+64) -> buffer m%3
  auto stageR = [&](int m) {
    const int d0 = base0 + 64 * m;
    int mr0 = d0 + row0; mr0 += (mr0 >= 1026) ? -1026 : 1023;
    mr0 = max(0, min(mr0, KLEN_ - 1));
    int mr1 = d0 + row1; mr1 += (mr1 >= 1026) ? -1026 : 1023;
    mr1 = max(0, min(mr1, KLEN_ - 1));
    bf16* dst = Rb[m % 3];
    GLDS(rh + (long)mr0 * DH_ + gch0 * 8, &dst[c0 * 8]);
    GLDS(rh + (long)mr1 * DH_ + gch1 * 8, &dst[c1 * 8]);
  };
  auto stageKV = [&](int k) {
    const int j0 = jbeg + 64 * k;
    bf16* kd = Kt[k & 1];
    bf16* vd = Vt[k & 1];
    GLDS(kbase + (long)(j0 + row0) * DH_ + gch0 * 8, &kd[c0 * 8]);
    GLDS(kbase + (long)(j0 + row1) * DH_ + gch1 * 8, &kd[c1 * 8]);
    GLDS(vbase + (long)row0 * KLEN_ + j0 + gch0 * 8, &vd[c0 * 8]);
    GLDS(vbase + (long)row1 * KLEN_ + j0 + gch1 * 8, &vd[c1 * 8]);
  };

  // prologue: tile 0 + both halves of its band
  stageKV(0);
  stageR(0);
  stageR(1);
  __syncthreads();

  for (int k = 0; k < NITER; ++k) {
    const int j0 = jbeg + 64 * k;
    // ---- STAGE next tile (other buffers; latency hides under compute) ----
    if (k + 1 < NITER) {
      stageKV(k + 1);
      stageR(k + 2);
    }
    // ---- ac = qw . K^T (from LDS) ----
    const bf16* kcur = Kt[k & 1];
    f32x4 s[4];
#pragma unroll
    for (int t = 0; t < 4; ++t) {
      const bf16x8 kb0 = *(const bf16x8*)&kcur[swz(16 * t + lo, lg)];
      const bf16x8 kb1 = *(const bf16x8*)&kcur[swz(16 * t + lo, lg + 4)];
      f32x4 z = {};
      z = MFMA16(aq0, kb0, z);
      z = MFMA16(aq1, kb1, z);
      s[t] = z;
    }
    // ---- bd band (rotating half-band buffers) ----
    const int dbase = j0 - i0 - 15;
    const int rlo = k % 3, rhi = (k + 1) % 3;
#pragma unroll
    for (int t = 0; t < 5; ++t) {
      const int dmin = dbase + 16 * t;
      const bool need1 = (dmin <= 1024);
      const bool need2 = (dmin + 15 >= 1026);
      const int dcol = dmin + lo;
      const int c = 48 - 16 * wid + 16 * t + lo;    // band col 0..127
      const bf16* rbase = Rb[(c < 64) ? rlo : rhi]; // per-lane select
      const bf16x8 rb0 = *(const bf16x8*)&rbase[swz(c & 63, lg)];
      const bf16x8 rb1 = *(const bf16x8*)&rbase[swz(c & 63, lg + 4)];
      f32x4 z1 = {}, z2 = {};
      if (need1) { z1 = MFMA16(ar0, rb0, z1); z1 = MFMA16(ar1, rb1, z1); }
      if (need2) {
        const int rs = min(i0 + 1 + lo, Q_ - 1);
        const bf16x8 as0 = *(const bf16x8*)&qr[(bh * Q_ + rs) * DH_ + lg * 8];
        const bf16x8 as1 = *(const bf16x8*)&qr[(bh * Q_ + rs) * DH_ + 32 + lg * 8];
        z2 = MFMA16(as0, rb0, z2);
        z2 = MFMA16(as1, rb1, z2);
      }
#pragma unroll
      for (int r = 0; r < 4; ++r) {
        float v = (dcol >= 1026) ? z2[r] : z1[r];
        if (dcol == 1025) v = 0.f;
        Sd[wid][lg * 4 + r][16 * t + lo] = f2bf(v);
      }
    }
    // ---- softmax (online, log2 domain) ----
    float mnew[4];
#pragma unroll
    for (int r = 0; r < 4; ++r) {
      const int row = lg * 4 + r;
      float mt = -1e30f;
#pragma unroll
      for (int t = 0; t < 4; ++t) {
        const float bd = bf2f(Sd[wid][row][16 * t + lo + 15 - row]);
        const float sc = s[t][r] + bd;
        s[t][r] = sc;
        mt = fmaxf(mt, sc);
      }
#pragma unroll
      for (int d = 1; d < 16; d <<= 1) mt = fmaxf(mt, __shfl_xor(mt, d));
      mnew[r] = fmaxf(mrun[r], mt);
    }
#pragma unroll
    for (int r = 0; r < 4; ++r) {
      float rsum = 0.f;
#pragma unroll
      for (int t = 0; t < 4; ++t) {
        const float p = ex2(s[t][r] - mnew[r]);
        s[t][r] = p;
        rsum += p;
      }
#pragma unroll
      for (int d = 1; d < 16; d <<= 1) rsum += __shfl_xor(rsum, d);
      const float scale = ex2(mrun[r] - mnew[r]);
      lrun[r] = lrun[r] * scale + rsum;
      mrun[r] = mnew[r];
#pragma unroll
      for (int u = 0; u < 4; ++u) o[u][r] *= scale;
    }
    // ---- P -> LDS -> A-frag, PV (V from LDS) ----
#pragma unroll
    for (int t = 0; t < 4; ++t)
#pragma unroll
      for (int r = 0; r < 4; ++r)
        Ps[wid][lg * 4 + r][16 * t + lo] = f2bf(s[t][r]);
    const bf16x8 pa0 = *(const bf16x8*)&Ps[wid][lo][lg * 8];
    const bf16x8 pa1 = *(const bf16x8*)&Ps[wid][lo][32 + lg * 8];
    const bf16* vcur = Vt[k & 1];
#pragma unroll
    for (int u = 0; u < 4; ++u) {
      const bf16x8 vb0 = *(const bf16x8*)&vcur[swz(16 * u + lo, lg)];
      const bf16x8 vb1 = *(const bf16x8*)&vcur[swz(16 * u + lo, lg + 4)];
      o[u] = MFMA16(pa0, vb0, o[u]);
      o[u] = MFMA16(pa1, vb1, o[u]);
    }
    // ONE barrier: drains vmcnt (next tiles become visible) and protects the
    // buffers compute(k) just read from being overwritten in iter k+1.
    __syncthreads();
  }
  // ---- partial outputs ----
#pragma unroll
  for (int u = 0; u < 4; ++u) {
#pragma unroll
    for (int r = 0; r < 4; ++r) {
      const int i = i0 + lg * 4 + r;
      po[(((long)(bh * Q_ + i)) * NSPLIT + js) * DH_ + 16 * u + lo] = o[u][r];
    }
  }
  if (lo == 0) {
#pragma unroll
    for (int r = 0; r < 4; ++r) {
      const int i = i0 + lg * 4 + r;
      pml[((long)(bh * Q_ + i)) * NSPLIT + js] = make_float2(mrun[r], lrun[r]);
    }
  }
}

// ---------------- combine partial softmax halves (log2 domain) -------------
__global__ __launch_bounds__(256) void combine_kernel(
    const float* __restrict__ po, const float2* __restrict__ pml,
    bf16* __restrict__ attnv) {
  const long gid = (long)blockIdx.x * 256 + threadIdx.x;  // B*H*Q*DH
  const int col = gid & 63;
  const long row = gid >> 6;  // bh*Q + i
  const float2 ml0 = pml[row * NSPLIT];
  const float2 ml1 = pml[row * NSPLIT + 1];
  const float m = fmaxf(ml0.x, ml1.x);
  const float w0 = ex2(ml0.x - m), w1 = ex2(ml1.x - m);
  const float num = po[(row * NSPLIT) * DH_ + col] * w0 +
                    po[(row * NSPLIT + 1) * DH_ + col] * w1;
  const float den = ml0.y * w0 + ml1.y * w1;
  const int b = (int)(row >> 14);
  const int h = (int)(row >> 10) & 15;
  const int i = (int)row & 1023;
  attnv[((long)(b * Q_ + i)) * D_ + h * DH_ + col] = f2bf(num / den);
}

// ---------------- host ----------------
extern "C" void kernel_launch(void* const* d_in, const int* in_sizes, int n_in,
                              void* d_out, int out_size, void* d_ws, size_t ws_size,
                              hipStream_t stream) {
  (void)in_sizes; (void)n_in; (void)out_size; (void)ws_size;
  const float* h_in  = (const float*)d_in[0];
  const float* mem_in= (const float*)d_in[1];
  const float* r_in  = (const float*)d_in[2];
  const float* Wq = (const float*)d_in[3];
  const float* Wk = (const float*)d_in[4];
  const float* Wv = (const float*)d_in[5];
  const float* Wr = (const float*)d_in[6];
  const float* Wo = (const float*)d_in[7];
  const float* rwb = (const float*)d_in[8];
  const float* rrb = (const float*)d_in[9];

  float* out = (float*)d_out;
  float* kcache = out + (long)B_ * Q_ * D_;
  float* vcache = kcache + (long)B_ * H_ * MEM_ * DH_;

  char* w = (char*)d_ws;
  auto alloc = [&](size_t bytes) {
    char* p = w;
    w += (bytes + 255) & ~(size_t)255;
    return p;
  };
  bf16* h_bf   = (bf16*)alloc((size_t)B_ * Q_ * D_ * 2);
  bf16* mem_bf = (bf16*)alloc((size_t)B_ * MEM_ * D_ * 2);
  bf16* r_bf   = (bf16*)alloc((size_t)KLEN_ * D_ * 2);
  bf16* Wqt = (bf16*)alloc((size_t)D_ * D_ * 2);
  bf16* Wkt = (bf16*)alloc((size_t)D_ * D_ * 2);
  bf16* Wvt = (bf16*)alloc((size_t)D_ * D_ * 2);
  bf16* Wrt = (bf16*)alloc((size_t)D_ * D_ * 2);
  bf16* Wot = (bf16*)alloc((size_t)D_ * D_ * 2);
  bf16* qw    = (bf16*)alloc((size_t)B_ * H_ * Q_ * DH_ * 2);
  bf16* qr    = (bf16*)alloc((size_t)B_ * H_ * Q_ * DH_ * 2);
  bf16* kall  = (bf16*)alloc((size_t)B_ * H_ * KLEN_ * DH_ * 2);
  bf16* vT    = (bf16*)alloc((size_t)B_ * H_ * KLEN_ * DH_ * 2);
  bf16* rhead = (bf16*)alloc((size_t)H_ * KLEN_ * DH_ * 2);
  bf16* attnv = (bf16*)alloc((size_t)B_ * Q_ * D_ * 2);
  float* po   = (float*)alloc((size_t)B_ * H_ * Q_ * NSPLIT * DH_ * 4);
  float2* pml = (float2*)alloc((size_t)B_ * H_ * Q_ * NSPLIT * 8);

  // 1. f32 -> bf16 conversions
  CvtArgs ca;
  ca.src[0] = h_in;   ca.dst[0] = h_bf;   ca.n4[0] = B_ * Q_ * D_ / 4;
  ca.src[1] = mem_in; ca.dst[1] = mem_bf; ca.n4[1] = B_ * MEM_ * D_ / 4;
  ca.src[2] = r_in;   ca.dst[2] = r_bf;   ca.n4[2] = KLEN_ * D_ / 4;
  cvt_kernel<<<dim3((B_ * Q_ * D_ / 4 + 255) / 256, 1, 3), 256, 0, stream>>>(ca);

  // 2. weight transposes
  TpArgs ta;
  ta.w[0] = Wq; ta.o[0] = Wqt;
  ta.w[1] = Wk; ta.o[1] = Wkt;
  ta.w[2] = Wv; ta.o[2] = Wvt;
  ta.w[3] = Wr; ta.o[3] = Wrt;
  ta.w[4] = Wo; ta.o[4] = Wot;
  tp_kernel<<<dim3(32, 32, 5), dim3(32, 8), 0, stream>>>(ta);

  GemmArgs g{};
  g.qw = qw; g.qr = qr; g.kall = kall; g.vT = vT; g.rhead = rhead;
  g.kcache = kcache; g.vcache = vcache; g.fout = out; g.rwb = rwb; g.rrb = rrb;

  // 3. h @ [Wq|Wk|Wv]  (M=4096, N=3072, K=1024)
  g.A = h_bf; g.Bt = Wqt; g.K = D_; g.batchA = 0; g.batchB = 0;
  gemm_bt<EPI_HQKV><<<dim3(3 * D_ / 128, B_ * Q_ / 128, 1), 256, 0, stream>>>(g);

  // 4. mem @ [Wk|Wv]  (M=4096, N=2048, K=1024)
  g.A = mem_bf; g.Bt = Wkt;
  gemm_bt<EPI_MEMKV><<<dim3(2 * D_ / 128, B_ * MEM_ / 128, 1), 256, 0, stream>>>(g);

  // 5. r @ Wr  (M=2048, N=1024, K=1024)
  g.A = r_bf; g.Bt = Wrt;
  gemm_bt<EPI_R><<<dim3(D_ / 128, KLEN_ / 128, 1), 256, 0, stream>>>(g);

  // 6. fused attention (KV-split, XCD-swizzled, pipelined LDS) + combine
  attn_kernel<<<dim3(Q_ / 64 * H_ * B_ * NSPLIT), 256, 0, stream>>>(
      qw, qr, kall, vT, rhead, po, pml);
  combine_kernel<<<dim3(B_ * H_ * Q_ * DH_ / 256), 256, 0, stream>>>(po, pml, attnv);

  // 7. out = attnv @ Wo  (M=4096, N=1024, K=1024)
  g.A = attnv; g.Bt = Wot; g.K = D_; g.batchA = 0; g.batchB = 0;
  gemm_bt<EPI_OUT><<<dim3(D_ / 128, B_ * Q_ / 128, 1), 256, 0, stream>>>(g);
}

// Round 10
// 415.817 us; speedup vs baseline: 1.0359x; 1.0182x over previous
//
#include <hip/hip_runtime.h>
#include <hip/hip_bf16.h>

#define B_ 4
#define Q_ 1024
#define MEM_ 1024
#define D_ 1024
#define H_ 16
#define DH_ 64
#define KLEN_ 2048
#define NSPLIT 2

typedef __hip_bfloat16 bf16;
typedef __bf16 bf16x8 __attribute__((ext_vector_type(8)));
typedef float f32x4 __attribute__((ext_vector_type(4)));

__device__ __forceinline__ float bf2f(bf16 x) { return __bfloat162float(x); }
__device__ __forceinline__ bf16 f2bf(float x) { return __float2bfloat16(x); }

// 2^x via v_exp_f32 (NOT __exp2f: glibc math.h macro collision, R7 lesson)
__device__ __forceinline__ float ex2(float x) { return __builtin_amdgcn_exp2f(x); }

// pack 2 f32 -> dword of 2 bf16 (no builtin on gfx950; T12 recipe)
__device__ __forceinline__ unsigned pkbf(float a, float b) {
  unsigned d;
  asm volatile("v_cvt_pk_bf16_f32 %0, %1, %2" : "=v"(d) : "v"(a), "v"(b));
  return d;
}

__device__ __forceinline__ unsigned short f2bf_bits(float x) {
  union { float f; unsigned u; } a; a.f = x;
  unsigned u = a.u;
  unsigned r = u + 0x7FFFu + ((u >> 16) & 1u);
  return (unsigned short)(r >> 16);
}

#define MFMA16(a, b, c) __builtin_amdgcn_mfma_f32_16x16x32_bf16((a), (b), (c), 0, 0, 0)
#define GLDS(gsrc, ldst) __builtin_amdgcn_global_load_lds( \
    (const __attribute__((address_space(1))) void*)(gsrc), \
    (__attribute__((address_space(3))) void*)(ldst), 16, 0, 0)

// swizzled LDS address for a 16B chunk: rows of 64 bf16 (128B = 8 chunks),
// chunk slot XORed with row&7 so column-slice b128 reads spread across banks
__device__ __forceinline__ int swz(int row, int ch) {
  return row * 64 + ((ch ^ (row & 7)) * 8);
}

// 0.125 (1/sqrt(DH)) * log2(e): scores land in log2 domain -> exp2 softmax
#define QSCALE 0.180336880111112f

// ---------------- conversions ----------------
struct CvtArgs { const float* src[3]; bf16* dst[3]; int n4[3]; };

__global__ void cvt_kernel(CvtArgs a) {
  const int z = blockIdx.z;
  const float4* s = (const float4*)a.src[z];
  const int n4 = a.n4[z];
  const int i = blockIdx.x * blockDim.x + threadIdx.x;
  if (i < n4) {
    float4 v = s[i];
    ushort4 o;
    o.x = f2bf_bits(v.x); o.y = f2bf_bits(v.y);
    o.z = f2bf_bits(v.z); o.w = f2bf_bits(v.w);
    ((ushort4*)a.dst[z])[i] = o;
  }
}

// ---------------- weight transpose (f32 -> bf16, Wt[n][k] = W[k][n]) -------
struct TpArgs { const float* w[5]; bf16* o[5]; };

__global__ void tp_kernel(TpArgs a) {
  __shared__ float t[32][33];
  const int z = blockIdx.z;
  const float* W = a.w[z];
  bf16* Wt = a.o[z];
  const int bx = blockIdx.x * 32, by = blockIdx.y * 32;
  const int tx = threadIdx.x, ty = threadIdx.y;
#pragma unroll
  for (int y = ty; y < 32; y += 8) t[y][tx] = W[(long)(by + y) * D_ + bx + tx];
  __syncthreads();
#pragma unroll
  for (int y = ty; y < 32; y += 8)
    Wt[(long)(bx + y) * D_ + by + tx] = f2bf(t[tx][y]);
}

// ---------------- GEMM (A row-major MxK bf16, Bt row-major NxK bf16) -------
enum { EPI_HQKV = 0, EPI_MEMKV, EPI_R, EPI_OUT };

struct GemmArgs {
  const bf16* A; const bf16* Bt;
  int K;
  long batchA, batchB;
  bf16 *qw, *qr, *kall, *vT, *rhead;
  float *kcache, *vcache, *fout;
  const float *rwb, *rrb;
};

template <int MODE>
__global__ __launch_bounds__(256) void gemm_bt(GemmArgs g) {
  __shared__ bf16 As[128 * 32];
  __shared__ bf16 Bs[128 * 32];
  const int tid = threadIdx.x;
  const int wid = tid >> 6, lane = tid & 63;
  const int wr = wid >> 1, wc = wid & 1;
  const int lo = lane & 15, lg = lane >> 4;
  const int m0 = blockIdx.y * 128, n0 = blockIdx.x * 128;
  const int K = g.K;
  const bf16* A = g.A + (long)blockIdx.z * g.batchA;
  const bf16* Bt = g.Bt + (long)blockIdx.z * g.batchB;

  f32x4 acc[4][4] = {};

  const int srow = 32 * wid + (lane >> 2);
  const int scol = (lane & 3) * 8;
  const bf16* asrc = A + (long)(m0 + srow) * K + scol;
  const bf16* bsrc = Bt + (long)(n0 + srow) * K + scol;
  bf16* adst0 = &As[(32 * wid) * 32];
  bf16* adst1 = &As[(32 * wid + 16) * 32];
  bf16* bdst0 = &Bs[(32 * wid) * 32];
  bf16* bdst1 = &Bs[(32 * wid + 16) * 32];

  for (int kt = 0; kt < K; kt += 32) {
    GLDS(asrc, adst0);
    GLDS(asrc + 16 * (long)K, adst1);
    GLDS(bsrc, bdst0);
    GLDS(bsrc + 16 * (long)K, bdst1);
    asrc += 32; bsrc += 32;
    __syncthreads();
    bf16x8 af[4], bfv[4];
#pragma unroll
    for (int m = 0; m < 4; ++m)
      af[m] = *(const bf16x8*)&As[(64 * wr + 16 * m + lo) * 32 + lg * 8];
#pragma unroll
    for (int n = 0; n < 4; ++n)
      bfv[n] = *(const bf16x8*)&Bs[(64 * wc + 16 * n + lo) * 32 + lg * 8];
#pragma unroll
    for (int m = 0; m < 4; ++m)
#pragma unroll
      for (int n = 0; n < 4; ++n)
        acc[m][n] = MFMA16(af[m], bfv[n], acc[m][n]);
    __syncthreads();
  }

#pragma unroll
  for (int m = 0; m < 4; ++m) {
#pragma unroll
    for (int n = 0; n < 4; ++n) {
#pragma unroll
      for (int r = 0; r < 4; ++r) {
        const float v = acc[m][n][r];
        const int gr = m0 + 64 * wr + 16 * m + lg * 4 + r;
        const int gc = n0 + 64 * wc + 16 * n + lo;
        if constexpr (MODE == EPI_HQKV) {
          const int b = gr >> 10, i = gr & 1023;
          const int seg = gc >> 10, c = gc & 1023;
          const int hh = c >> 6, dh = c & 63;
          const long bh = (long)(b * H_ + hh);
          if (seg == 0) {
            // fold 1/sqrt(DH) * log2(e) into q: scores in log2 domain
            const long idx = (bh * Q_ + i) * DH_ + dh;
            g.qw[idx] = f2bf((v + g.rwb[c]) * QSCALE);
            g.qr[idx] = f2bf((v + g.rrb[c]) * QSCALE);
          } else if (seg == 1) {
            g.kall[(bh * KLEN_ + MEM_ + i) * DH_ + dh] = f2bf(v);
            g.kcache[(bh * MEM_ + i) * DH_ + dh] = v;
          } else {
            g.vT[(bh * DH_ + dh) * KLEN_ + MEM_ + i] = f2bf(v);
            g.vcache[(bh * MEM_ + i) * DH_ + dh] = v;
          }
        } else if constexpr (MODE == EPI_MEMKV) {
          const int b = gr >> 10, i = gr & 1023;
          const int seg = gc >> 10, c = gc & 1023;
          const int hh = c >> 6, dh = c & 63;
          const long bh = (long)(b * H_ + hh);
          if (seg == 0) g.kall[(bh * KLEN_ + i) * DH_ + dh] = f2bf(v);
          else          g.vT[(bh * DH_ + dh) * KLEN_ + i] = f2bf(v);
        } else if constexpr (MODE == EPI_R) {
          const int hh = gc >> 6, dh = gc & 63;
          g.rhead[((long)hh * KLEN_ + gr) * DH_ + dh] = f2bf(v);
        } else {  // EPI_OUT
          g.fout[(long)gr * D_ + gc] = v;
        }
      }
    }
  }
}

// ---------------- fused attention: swapped-operand S^T form ----------------
// R6 staging structure (LDS-shared K/V/R band, 2 barriers/iter, 3 blocks/CU)
// but ALL MFMAs operand-swapped: mfma(K,Q), mfma(R,qr), mfma(V,P). Each lane
// then owns one full q-row (i = i0+lo): softmax reduce = 15 serial fmax/add +
// 2 shfl (was 32 shfl); mrun/lrun/o-rescale lane-local scalars; Sd/Ps LDS
// round-trips use packed-dword cvt_pk writes (halved scalar DS traffic);
// output stores become float4. Targets the DS-pipe bound diagnosed in R9.
__global__ __launch_bounds__(256) void attn_kernel(
    const bf16* __restrict__ qw, const bf16* __restrict__ qr,
    const bf16* __restrict__ kall, const bf16* __restrict__ vT,
    const bf16* __restrict__ rhead, float* __restrict__ po,
    float2* __restrict__ pml) {
  __shared__ bf16 Kt[64 * 64];
  __shared__ bf16 Vt[64 * 64];
  __shared__ bf16 Rt[128 * 64];
  __shared__ bf16 Sd[4][16][86];  // [wave][i-row][band col c, stride 86 for odd-bank spread]
  __shared__ bf16 Ps[4][16][72];  // packed P, XOR-group swizzled dwords
  const int hw = blockIdx.x;
  const int L = ((hw & 7) << 8) | (hw >> 3);
  const int xb = L & 15;
  const int h = (L >> 4) & 15;
  const int js = (L >> 8) & 1;
  const int b = L >> 9;
  const int tid = threadIdx.x;
  const int wid = tid >> 6, lane = tid & 63;
  const int lo = lane & 15, lg = lane >> 4;
  const int I0 = xb * 64;
  const int i0 = I0 + wid * 16;
  const long bh = (long)(b * H_ + h);
  const bf16* rh = rhead + (long)h * KLEN_ * DH_;
  const bf16* kbase = kall + bh * KLEN_ * DH_;
  const bf16* vbase = vT + bh * DH_ * KLEN_;

  const bf16x8 aq0 = *(const bf16x8*)&qw[(bh * Q_ + i0 + lo) * DH_ + lg * 8];
  const bf16x8 aq1 = *(const bf16x8*)&qw[(bh * Q_ + i0 + lo) * DH_ + 32 + lg * 8];
  const bf16x8 ar0 = *(const bf16x8*)&qr[(bh * Q_ + i0 + lo) * DH_ + lg * 8];
  const bf16x8 ar1 = *(const bf16x8*)&qr[(bh * Q_ + i0 + lo) * DH_ + 32 + lg * 8];

  f32x4 o[4] = {};
  float mrun = -1e30f, lrun = 0.f;  // lane-local: one q-row per lane

  const int jbeg = js << 10, jend = jbeg + (KLEN_ / NSPLIT);
  for (int j0 = jbeg; j0 < jend; j0 += 64) {
    // ---- STAGE: K (2 chunks/thread), V (2), rhead band (4) [R6 exact] ----
    const int d0 = j0 - I0 - 63;  // Rt[row] = rhead[m(d0+row)]
#pragma unroll
    for (int ss = 0; ss < 2; ++ss) {
      const int c = tid + ss * 256;
      const int row = c >> 3;
      const int gch = (c & 7) ^ (row & 7);
      GLDS(kbase + (long)(j0 + row) * DH_ + gch * 8, &Kt[c * 8]);
    }
#pragma unroll
    for (int ss = 0; ss < 2; ++ss) {
      const int c = tid + ss * 256;
      const int row = c >> 3;
      const int gch = (c & 7) ^ (row & 7);
      GLDS(vbase + (long)row * KLEN_ + j0 + gch * 8, &Vt[c * 8]);
    }
#pragma unroll
    for (int ss = 0; ss < 4; ++ss) {
      const int c = tid + ss * 256;
      const int row = c >> 3;
      const int dcol = d0 + row;
      int m = dcol + ((dcol >= 1026) ? -1026 : 1023);
      m = max(0, min(m, KLEN_ - 1));
      const int gch = (c & 7) ^ (row & 7);
      GLDS(rh + (long)m * DH_ + gch * 8, &Rt[c * 8]);
    }
    __syncthreads();

    // ---- QK^T swapped: s[t][r] = S[i=i0+lo][j=j0+16t+4lg+r] ----
    f32x4 s[4];
#pragma unroll
    for (int t = 0; t < 4; ++t) {
      const bf16x8 kb0 = *(const bf16x8*)&Kt[swz(16 * t + lo, lg)];
      const bf16x8 kb1 = *(const bf16x8*)&Kt[swz(16 * t + lo, lg + 4)];
      f32x4 z = {};
      z = MFMA16(kb0, aq0, z);
      z = MFMA16(kb1, aq1, z);
      s[t] = z;
    }
    // ---- BD swapped: D[c][i]; lane holds c=crow0+16t+4lg+r, i=i0+lo ----
    const int crow0 = 48 - 16 * wid;
#pragma unroll
    for (int t = 0; t < 5; ++t) {
      const int dtb = d0 + crow0 + 16 * t;  // delta at tile row 0 (wave-uniform)
      const bool need1 = (dtb <= 1024);
      const bool need2 = (dtb + 15 >= 1026);
      const int c = crow0 + 16 * t + lo;    // Rt row for A-frag (same as old)
      const bf16x8 rb0 = *(const bf16x8*)&Rt[swz(c, lg)];
      const bf16x8 rb1 = *(const bf16x8*)&Rt[swz(c, lg + 4)];
      f32x4 z1 = {}, z2 = {};
      if (need1) { z1 = MFMA16(rb0, ar0, z1); z1 = MFMA16(rb1, ar1, z1); }
      if (need2) {
        const int rs = min(i0 + 1 + lo, Q_ - 1);  // clamped rows never consumed
        const bf16x8 as0 = *(const bf16x8*)&qr[(bh * Q_ + rs) * DH_ + lg * 8];
        const bf16x8 as1 = *(const bf16x8*)&qr[(bh * Q_ + rs) * DH_ + 32 + lg * 8];
        z2 = MFMA16(rb0, as0, z2);
        z2 = MFMA16(rb1, as1, z2);
      }
      float v0, v1, v2, v3;
      {
        const int dlt0 = dtb + 4 * lg;
        v0 = (dlt0 + 0 >= 1026) ? z2[0] : z1[0]; if (dlt0 + 0 == 1025) v0 = 0.f;
        v1 = (dlt0 + 1 >= 1026) ? z2[1] : z1[1]; if (dlt0 + 1 == 1025) v1 = 0.f;
        v2 = (dlt0 + 2 >= 1026) ? z2[2] : z1[2]; if (dlt0 + 2 == 1025) v2 = 0.f;
        v3 = (dlt0 + 3 >= 1026) ? z2[3] : z1[3]; if (dlt0 + 3 == 1025) v3 = 0.f;
      }
      // packed dword writes into own row lo, cols 16t+4lg .. +3
      *(unsigned*)&Sd[wid][lo][16 * t + 4 * lg]     = pkbf(v0, v1);
      *(unsigned*)&Sd[wid][lo][16 * t + 4 * lg + 2] = pkbf(v2, v3);
    }
    // ---- softmax: row i=i0+lo lane-local; reduce over lg-quad only ----
    float mt = -1e30f;
#pragma unroll
    for (int t = 0; t < 4; ++t)
#pragma unroll
      for (int r = 0; r < 4; ++r) {
        const float bd = bf2f(Sd[wid][lo][16 * t + 4 * lg + r - lo + 15]);
        s[t][r] += bd;
        mt = fmaxf(mt, s[t][r]);
      }
    mt = fmaxf(mt, __shfl_xor(mt, 16));
    mt = fmaxf(mt, __shfl_xor(mt, 32));
    const float mnew = fmaxf(mrun, mt);
    const float scale = ex2(mrun - mnew);
    float rsum = 0.f;
#pragma unroll
    for (int t = 0; t < 4; ++t)
#pragma unroll
      for (int r = 0; r < 4; ++r) {
        const float p = ex2(s[t][r] - mnew);
        s[t][r] = p;
        rsum += p;
      }
    rsum += __shfl_xor(rsum, 16);
    rsum += __shfl_xor(rsum, 32);
    lrun = lrun * scale + rsum;
    mrun = mnew;
#pragma unroll
    for (int u = 0; u < 4; ++u)
#pragma unroll
      for (int r = 0; r < 4; ++r) o[u][r] *= scale;
    // ---- P pack -> Ps (XOR-group-swizzled dwords), read as B-frag ----
    const int xw = lo & 7;
#pragma unroll
    for (int t = 0; t < 4; ++t) {
      const unsigned p0 = pkbf(s[t][0], s[t][1]);
      const unsigned p1 = pkbf(s[t][2], s[t][3]);
      const int c0 = 8 * t + 2 * lg;  // logical dword col (c1 = c0+1, same group)
      const int grp = ((c0 >> 2) ^ xw) & 7;
      const int q0 = (c0 & 3) | (grp << 2);
      *(unsigned*)&Ps[wid][lo][2 * q0]     = p0;
      *(unsigned*)&Ps[wid][lo][2 * q0 + 2] = p1;
    }
    const bf16x8 pa0 = *(const bf16x8*)&Ps[wid][lo][8 * (lg ^ xw)];
    const bf16x8 pa1 = *(const bf16x8*)&Ps[wid][lo][8 * ((lg + 4) ^ xw)];
    // ---- PV swapped: o[u] accumulates O^T[d=16u+4lg+r][i=i0+lo] ----
#pragma unroll
    for (int u = 0; u < 4; ++u) {
      const bf16x8 vb0 = *(const bf16x8*)&Vt[swz(16 * u + lo, lg)];
      const bf16x8 vb1 = *(const bf16x8*)&Vt[swz(16 * u + lo, lg + 4)];
      o[u] = MFMA16(vb0, pa0, o[u]);
      o[u] = MFMA16(vb1, pa1, o[u]);
    }
    __syncthreads();  // protect Kt/Vt/Rt before next stage overwrites
  }
  // ---- partial outputs: contiguous d per lane -> float4 stores ----
  const int i = i0 + lo;
  const long obase = (((long)(bh * Q_ + i)) * NSPLIT + js) * DH_;
#pragma unroll
  for (int u = 0; u < 4; ++u)
    *(f32x4*)&po[obase + 16 * u + 4 * lg] = o[u];
  if (lg == 0)
    pml[((long)(bh * Q_ + i)) * NSPLIT + js] = make_float2(mrun, lrun);
}

// ---------------- combine partial softmax halves (log2 domain) -------------
__global__ __launch_bounds__(256) void combine_kernel(
    const float* __restrict__ po, const float2* __restrict__ pml,
    bf16* __restrict__ attnv) {
  const long gid = (long)blockIdx.x * 256 + threadIdx.x;  // B*H*Q*DH
  const int col = gid & 63;
  const long row = gid >> 6;  // bh*Q + i
  const float2 ml0 = pml[row * NSPLIT];
  const float2 ml1 = pml[row * NSPLIT + 1];
  const float m = fmaxf(ml0.x, ml1.x);
  const float w0 = ex2(ml0.x - m), w1 = ex2(ml1.x - m);
  const float num = po[(row * NSPLIT) * DH_ + col] * w0 +
                    po[(row * NSPLIT + 1) * DH_ + col] * w1;
  const float den = ml0.y * w0 + ml1.y * w1;
  const int b = (int)(row >> 14);
  const int h = (int)(row >> 10) & 15;
  const int i = (int)row & 1023;
  attnv[((long)(b * Q_ + i)) * D_ + h * DH_ + col] = f2bf(num / den);
}

// ---------------- host ----------------
extern "C" void kernel_launch(void* const* d_in, const int* in_sizes, int n_in,
                              void* d_out, int out_size, void* d_ws, size_t ws_size,
                              hipStream_t stream) {
  (void)in_sizes; (void)n_in; (void)out_size; (void)ws_size;
  const float* h_in  = (const float*)d_in[0];
  const float* mem_in= (const float*)d_in[1];
  const float* r_in  = (const float*)d_in[2];
  const float* Wq = (const float*)d_in[3];
  const float* Wk = (const float*)d_in[4];
  const float* Wv = (const float*)d_in[5];
  const float* Wr = (const float*)d_in[6];
  const float* Wo = (const float*)d_in[7];
  const float* rwb = (const float*)d_in[8];
  const float* rrb = (const float*)d_in[9];

  float* out = (float*)d_out;
  float* kcache = out + (long)B_ * Q_ * D_;
  float* vcache = kcache + (long)B_ * H_ * MEM_ * DH_;

  char* w = (char*)d_ws;
  auto alloc = [&](size_t bytes) {
    char* p = w;
    w += (bytes + 255) & ~(size_t)255;
    return p;
  };
  bf16* h_bf   = (bf16*)alloc((size_t)B_ * Q_ * D_ * 2);
  bf16* mem_bf = (bf16*)alloc((size_t)B_ * MEM_ * D_ * 2);
  bf16* r_bf   = (bf16*)alloc((size_t)KLEN_ * D_ * 2);
  bf16* Wqt = (bf16*)alloc((size_t)D_ * D_ * 2);
  bf16* Wkt = (bf16*)alloc((size_t)D_ * D_ * 2);
  bf16* Wvt = (bf16*)alloc((size_t)D_ * D_ * 2);
  bf16* Wrt = (bf16*)alloc((size_t)D_ * D_ * 2);
  bf16* Wot = (bf16*)alloc((size_t)D_ * D_ * 2);
  bf16* qw    = (bf16*)alloc((size_t)B_ * H_ * Q_ * DH_ * 2);
  bf16* qr    = (bf16*)alloc((size_t)B_ * H_ * Q_ * DH_ * 2);
  bf16* kall  = (bf16*)alloc((size_t)B_ * H_ * KLEN_ * DH_ * 2);
  bf16* vT    = (bf16*)alloc((size_t)B_ * H_ * KLEN_ * DH_ * 2);
  bf16* rhead = (bf16*)alloc((size_t)H_ * KLEN_ * DH_ * 2);
  bf16* attnv = (bf16*)alloc((size_t)B_ * Q_ * D_ * 2);
  float* po   = (float*)alloc((size_t)B_ * H_ * Q_ * NSPLIT * DH_ * 4);
  float2* pml = (float2*)alloc((size_t)B_ * H_ * Q_ * NSPLIT * 8);

  // 1. f32 -> bf16 conversions
  CvtArgs ca;
  ca.src[0] = h_in;   ca.dst[0] = h_bf;   ca.n4[0] = B_ * Q_ * D_ / 4;
  ca.src[1] = mem_in; ca.dst[1] = mem_bf; ca.n4[1] = B_ * MEM_ * D_ / 4;
  ca.src[2] = r_in;   ca.dst[2] = r_bf;   ca.n4[2] = KLEN_ * D_ / 4;
  cvt_kernel<<<dim3((B_ * Q_ * D_ / 4 + 255) / 256, 1, 3), 256, 0, stream>>>(ca);

  // 2. weight transposes
  TpArgs ta;
  ta.w[0] = Wq; ta.o[0] = Wqt;
  ta.w[1] = Wk; ta.o[1] = Wkt;
  ta.w[2] = Wv; ta.o[2] = Wvt;
  ta.w[3] = Wr; ta.o[3] = Wrt;
  ta.w[4] = Wo; ta.o[4] = Wot;
  tp_kernel<<<dim3(32, 32, 5), dim3(32, 8), 0, stream>>>(ta);

  GemmArgs g{};
  g.qw = qw; g.qr = qr; g.kall = kall; g.vT = vT; g.rhead = rhead;
  g.kcache = kcache; g.vcache = vcache; g.fout = out; g.rwb = rwb; g.rrb = rrb;

  // 3. h @ [Wq|Wk|Wv]  (M=4096, N=3072, K=1024)
  g.A = h_bf; g.Bt = Wqt; g.K = D_; g.batchA = 0; g.batchB = 0;
  gemm_bt<EPI_HQKV><<<dim3(3 * D_ / 128, B_ * Q_ / 128, 1), 256, 0, stream>>>(g);

  // 4. mem @ [Wk|Wv]  (M=4096, N=2048, K=1024)
  g.A = mem_bf; g.Bt = Wkt;
  gemm_bt<EPI_MEMKV><<<dim3(2 * D_ / 128, B_ * MEM_ / 128, 1), 256, 0, stream>>>(g);

  // 5. r @ Wr  (M=2048, N=1024, K=1024)
  g.A = r_bf; g.Bt = Wrt;
  gemm_bt<EPI_R><<<dim3(D_ / 128, KLEN_ / 128, 1), 256, 0, stream>>>(g);

  // 6. fused attention (KV-split, XCD-swizzled, swapped-operand) + combine
  attn_kernel<<<dim3(Q_ / 64 * H_ * B_ * NSPLIT), 256, 0, stream>>>(
      qw, qr, kall, vT, rhead, po, pml);
  combine_kernel<<<dim3(B_ * H_ * Q_ * DH_ / 256), 256, 0, stream>>>(po, pml, attnv);

  // 7. out = attnv @ Wo  (M=4096, N=1024, K=1024)
  g.A = attnv; g.Bt = Wot; g.K = D_; g.batchA = 0; g.batchB = 0;
  gemm_bt<EPI_OUT><<<dim3(D_ / 128, B_ * Q_ / 128, 1), 256, 0, stream>>>(g);
}

// Round 11
// 398.060 us; speedup vs baseline: 1.0821x; 1.0446x over previous
//
#include <hip/hip_runtime.h>
#include <hip/hip_bf16.h>

#define B_ 4
#define Q_ 1024
#define MEM_ 1024
#define D_ 1024
#define H_ 16
#define DH_ 64
#define KLEN_ 2048
#define NSPLIT 2

typedef __hip_bfloat16 bf16;
typedef __bf16 bf16x8 __attribute__((ext_vector_type(8)));
typedef float f32x4 __attribute__((ext_vector_type(4)));

__device__ __forceinline__ float bf2f(bf16 x) { return __bfloat162float(x); }
__device__ __forceinline__ bf16 f2bf(float x) { return __float2bfloat16(x); }

// 2^x via v_exp_f32 (NOT __exp2f: glibc math.h macro collision, R7 lesson)
__device__ __forceinline__ float ex2(float x) { return __builtin_amdgcn_exp2f(x); }

// pack 2 f32 -> dword of 2 bf16 (no builtin on gfx950; T12 recipe)
__device__ __forceinline__ unsigned pkbf(float a, float b) {
  unsigned d;
  asm volatile("v_cvt_pk_bf16_f32 %0, %1, %2" : "=v"(d) : "v"(a), "v"(b));
  return d;
}

__device__ __forceinline__ unsigned short f2bf_bits(float x) {
  union { float f; unsigned u; } a; a.f = x;
  unsigned u = a.u;
  unsigned r = u + 0x7FFFu + ((u >> 16) & 1u);
  return (unsigned short)(r >> 16);
}

#define MFMA16(a, b, c) __builtin_amdgcn_mfma_f32_16x16x32_bf16((a), (b), (c), 0, 0, 0)
#define GLDS(gsrc, ldst) __builtin_amdgcn_global_load_lds( \
    (const __attribute__((address_space(1))) void*)(gsrc), \
    (__attribute__((address_space(3))) void*)(ldst), 16, 0, 0)

// swizzled LDS address for a 16B chunk: rows of 64 bf16 (128B = 8 chunks),
// chunk slot XORed with row&7 so column-slice b128 reads spread across banks
__device__ __forceinline__ int swz(int row, int ch) {
  return row * 64 + ((ch ^ (row & 7)) * 8);
}

// 0.125 (1/sqrt(DH)) * log2(e): scores land in log2 domain -> exp2 softmax
#define QSCALE 0.180336880111112f

// ---------------- conversions ----------------
struct CvtArgs { const float* src[3]; bf16* dst[3]; int n4[3]; };

__global__ void cvt_kernel(CvtArgs a) {
  const int z = blockIdx.z;
  const float4* s = (const float4*)a.src[z];
  const int n4 = a.n4[z];
  const int i = blockIdx.x * blockDim.x + threadIdx.x;
  if (i < n4) {
    float4 v = s[i];
    ushort4 o;
    o.x = f2bf_bits(v.x); o.y = f2bf_bits(v.y);
    o.z = f2bf_bits(v.z); o.w = f2bf_bits(v.w);
    ((ushort4*)a.dst[z])[i] = o;
  }
}

// ---------------- weight transpose (f32 -> bf16, Wt[n][k] = W[k][n]) -------
struct TpArgs { const float* w[5]; bf16* o[5]; };

__global__ void tp_kernel(TpArgs a) {
  __shared__ float t[32][33];
  const int z = blockIdx.z;
  const float* W = a.w[z];
  bf16* Wt = a.o[z];
  const int bx = blockIdx.x * 32, by = blockIdx.y * 32;
  const int tx = threadIdx.x, ty = threadIdx.y;
#pragma unroll
  for (int y = ty; y < 32; y += 8) t[y][tx] = W[(long)(by + y) * D_ + bx + tx];
  __syncthreads();
#pragma unroll
  for (int y = ty; y < 32; y += 8)
    Wt[(long)(bx + y) * D_ + by + tx] = f2bf(t[tx][y]);
}

// ---------------- GEMM (A row-major MxK bf16, Bt row-major NxK bf16) -------
enum { EPI_HQKV = 0, EPI_MEMKV, EPI_R, EPI_OUT };

struct GemmArgs {
  const bf16* A; const bf16* Bt;
  int K;
  long batchA, batchB;
  bf16 *qw, *qr, *kall, *vT, *rhead;
  float *kcache, *vcache, *fout;
  const float *rwb, *rrb;
};

template <int MODE>
__global__ __launch_bounds__(256) void gemm_bt(GemmArgs g) {
  __shared__ bf16 As[128 * 32];
  __shared__ bf16 Bs[128 * 32];
  const int tid = threadIdx.x;
  const int wid = tid >> 6, lane = tid & 63;
  const int wr = wid >> 1, wc = wid & 1;
  const int lo = lane & 15, lg = lane >> 4;
  const int m0 = blockIdx.y * 128, n0 = blockIdx.x * 128;
  const int K = g.K;
  const bf16* A = g.A + (long)blockIdx.z * g.batchA;
  const bf16* Bt = g.Bt + (long)blockIdx.z * g.batchB;

  f32x4 acc[4][4] = {};

  const int srow = 32 * wid + (lane >> 2);
  const int scol = (lane & 3) * 8;
  const bf16* asrc = A + (long)(m0 + srow) * K + scol;
  const bf16* bsrc = Bt + (long)(n0 + srow) * K + scol;
  bf16* adst0 = &As[(32 * wid) * 32];
  bf16* adst1 = &As[(32 * wid + 16) * 32];
  bf16* bdst0 = &Bs[(32 * wid) * 32];
  bf16* bdst1 = &Bs[(32 * wid + 16) * 32];

  for (int kt = 0; kt < K; kt += 32) {
    GLDS(asrc, adst0);
    GLDS(asrc + 16 * (long)K, adst1);
    GLDS(bsrc, bdst0);
    GLDS(bsrc + 16 * (long)K, bdst1);
    asrc += 32; bsrc += 32;
    __syncthreads();
    bf16x8 af[4], bfv[4];
#pragma unroll
    for (int m = 0; m < 4; ++m)
      af[m] = *(const bf16x8*)&As[(64 * wr + 16 * m + lo) * 32 + lg * 8];
#pragma unroll
    for (int n = 0; n < 4; ++n)
      bfv[n] = *(const bf16x8*)&Bs[(64 * wc + 16 * n + lo) * 32 + lg * 8];
#pragma unroll
    for (int m = 0; m < 4; ++m)
#pragma unroll
      for (int n = 0; n < 4; ++n)
        acc[m][n] = MFMA16(af[m], bfv[n], acc[m][n]);
    __syncthreads();
  }

#pragma unroll
  for (int m = 0; m < 4; ++m) {
#pragma unroll
    for (int n = 0; n < 4; ++n) {
#pragma unroll
      for (int r = 0; r < 4; ++r) {
        const float v = acc[m][n][r];
        const int gr = m0 + 64 * wr + 16 * m + lg * 4 + r;
        const int gc = n0 + 64 * wc + 16 * n + lo;
        if constexpr (MODE == EPI_HQKV) {
          const int b = gr >> 10, i = gr & 1023;
          const int seg = gc >> 10, c = gc & 1023;
          const int hh = c >> 6, dh = c & 63;
          const long bh = (long)(b * H_ + hh);
          if (seg == 0) {
            // fold 1/sqrt(DH) * log2(e) into q: scores in log2 domain
            const long idx = (bh * Q_ + i) * DH_ + dh;
            g.qw[idx] = f2bf((v + g.rwb[c]) * QSCALE);
            g.qr[idx] = f2bf((v + g.rrb[c]) * QSCALE);
          } else if (seg == 1) {
            g.kall[(bh * KLEN_ + MEM_ + i) * DH_ + dh] = f2bf(v);
            g.kcache[(bh * MEM_ + i) * DH_ + dh] = v;
          } else {
            g.vT[(bh * DH_ + dh) * KLEN_ + MEM_ + i] = f2bf(v);
            g.vcache[(bh * MEM_ + i) * DH_ + dh] = v;
          }
        } else if constexpr (MODE == EPI_MEMKV) {
          const int b = gr >> 10, i = gr & 1023;
          const int seg = gc >> 10, c = gc & 1023;
          const int hh = c >> 6, dh = c & 63;
          const long bh = (long)(b * H_ + hh);
          if (seg == 0) g.kall[(bh * KLEN_ + i) * DH_ + dh] = f2bf(v);
          else          g.vT[(bh * DH_ + dh) * KLEN_ + i] = f2bf(v);
        } else if constexpr (MODE == EPI_R) {
          const int hh = gc >> 6, dh = gc & 63;
          g.rhead[((long)hh * KLEN_ + gr) * DH_ + dh] = f2bf(v);
        } else {  // EPI_OUT
          g.fout[(long)gr * D_ + gc] = v;
        }
      }
    }
  }
}

// ---------------- fused attention: swapped-operand S^T form ----------------
// R10 structure with the two regression sources repaired: (1) Ps uses the
// R6-proven plain stride-72 pattern (packed dword writes at [lo][16t+4lg],
// b128 reads at [lo][8lg]) -- the speculative xw-XOR doubled bank conflicts;
// (2) row max/sum use depth-3 trees instead of 15-op serial chains.
__global__ __launch_bounds__(256) void attn_kernel(
    const bf16* __restrict__ qw, const bf16* __restrict__ qr,
    const bf16* __restrict__ kall, const bf16* __restrict__ vT,
    const bf16* __restrict__ rhead, float* __restrict__ po,
    float2* __restrict__ pml) {
  __shared__ bf16 Kt[64 * 64];
  __shared__ bf16 Vt[64 * 64];
  __shared__ bf16 Rt[128 * 64];
  __shared__ bf16 Sd[4][16][86];  // [wave][i-row][band col], stride 86
  __shared__ bf16 Ps[4][16][72];  // [wave][i-row][j col], stride 72 (R6 pattern)
  const int hw = blockIdx.x;
  const int L = ((hw & 7) << 8) | (hw >> 3);
  const int xb = L & 15;
  const int h = (L >> 4) & 15;
  const int js = (L >> 8) & 1;
  const int b = L >> 9;
  const int tid = threadIdx.x;
  const int wid = tid >> 6, lane = tid & 63;
  const int lo = lane & 15, lg = lane >> 4;
  const int I0 = xb * 64;
  const int i0 = I0 + wid * 16;
  const long bh = (long)(b * H_ + h);
  const bf16* rh = rhead + (long)h * KLEN_ * DH_;
  const bf16* kbase = kall + bh * KLEN_ * DH_;
  const bf16* vbase = vT + bh * DH_ * KLEN_;

  const bf16x8 aq0 = *(const bf16x8*)&qw[(bh * Q_ + i0 + lo) * DH_ + lg * 8];
  const bf16x8 aq1 = *(const bf16x8*)&qw[(bh * Q_ + i0 + lo) * DH_ + 32 + lg * 8];
  const bf16x8 ar0 = *(const bf16x8*)&qr[(bh * Q_ + i0 + lo) * DH_ + lg * 8];
  const bf16x8 ar1 = *(const bf16x8*)&qr[(bh * Q_ + i0 + lo) * DH_ + 32 + lg * 8];

  f32x4 o[4] = {};
  float mrun = -1e30f, lrun = 0.f;  // lane-local: one q-row per lane

  const int jbeg = js << 10, jend = jbeg + (KLEN_ / NSPLIT);
  for (int j0 = jbeg; j0 < jend; j0 += 64) {
    // ---- STAGE: K (2 chunks/thread), V (2), rhead band (4) [R6 exact] ----
    const int d0 = j0 - I0 - 63;  // Rt[row] = rhead[m(d0+row)]
#pragma unroll
    for (int ss = 0; ss < 2; ++ss) {
      const int c = tid + ss * 256;
      const int row = c >> 3;
      const int gch = (c & 7) ^ (row & 7);
      GLDS(kbase + (long)(j0 + row) * DH_ + gch * 8, &Kt[c * 8]);
    }
#pragma unroll
    for (int ss = 0; ss < 2; ++ss) {
      const int c = tid + ss * 256;
      const int row = c >> 3;
      const int gch = (c & 7) ^ (row & 7);
      GLDS(vbase + (long)row * KLEN_ + j0 + gch * 8, &Vt[c * 8]);
    }
#pragma unroll
    for (int ss = 0; ss < 4; ++ss) {
      const int c = tid + ss * 256;
      const int row = c >> 3;
      const int dcol = d0 + row;
      int m = dcol + ((dcol >= 1026) ? -1026 : 1023);
      m = max(0, min(m, KLEN_ - 1));
      const int gch = (c & 7) ^ (row & 7);
      GLDS(rh + (long)m * DH_ + gch * 8, &Rt[c * 8]);
    }
    __syncthreads();

    // ---- QK^T swapped: s[t][r] = S[i=i0+lo][j=j0+16t+4lg+r] ----
    f32x4 s[4];
#pragma unroll
    for (int t = 0; t < 4; ++t) {
      const bf16x8 kb0 = *(const bf16x8*)&Kt[swz(16 * t + lo, lg)];
      const bf16x8 kb1 = *(const bf16x8*)&Kt[swz(16 * t + lo, lg + 4)];
      f32x4 z = {};
      z = MFMA16(kb0, aq0, z);
      z = MFMA16(kb1, aq1, z);
      s[t] = z;
    }
    // ---- BD swapped: D[c][i]; lane holds c=crow0+16t+4lg+r, i=i0+lo ----
    const int crow0 = 48 - 16 * wid;
#pragma unroll
    for (int t = 0; t < 5; ++t) {
      const int dtb = d0 + crow0 + 16 * t;  // delta at tile row 0 (wave-uniform)
      const bool need1 = (dtb <= 1024);
      const bool need2 = (dtb + 15 >= 1026);
      const int c = crow0 + 16 * t + lo;    // Rt row for A-frag
      const bf16x8 rb0 = *(const bf16x8*)&Rt[swz(c, lg)];
      const bf16x8 rb1 = *(const bf16x8*)&Rt[swz(c, lg + 4)];
      f32x4 z1 = {}, z2 = {};
      if (need1) { z1 = MFMA16(rb0, ar0, z1); z1 = MFMA16(rb1, ar1, z1); }
      if (need2) {
        const int rs = min(i0 + 1 + lo, Q_ - 1);  // clamped rows never consumed
        const bf16x8 as0 = *(const bf16x8*)&qr[(bh * Q_ + rs) * DH_ + lg * 8];
        const bf16x8 as1 = *(const bf16x8*)&qr[(bh * Q_ + rs) * DH_ + 32 + lg * 8];
        z2 = MFMA16(rb0, as0, z2);
        z2 = MFMA16(rb1, as1, z2);
      }
      float v0, v1, v2, v3;
      {
        const int dlt0 = dtb + 4 * lg;
        v0 = (dlt0 + 0 >= 1026) ? z2[0] : z1[0]; if (dlt0 + 0 == 1025) v0 = 0.f;
        v1 = (dlt0 + 1 >= 1026) ? z2[1] : z1[1]; if (dlt0 + 1 == 1025) v1 = 0.f;
        v2 = (dlt0 + 2 >= 1026) ? z2[2] : z1[2]; if (dlt0 + 2 == 1025) v2 = 0.f;
        v3 = (dlt0 + 3 >= 1026) ? z2[3] : z1[3]; if (dlt0 + 3 == 1025) v3 = 0.f;
      }
      // packed dword writes into own row lo, cols 16t+4lg .. +3
      *(unsigned*)&Sd[wid][lo][16 * t + 4 * lg]     = pkbf(v0, v1);
      *(unsigned*)&Sd[wid][lo][16 * t + 4 * lg + 2] = pkbf(v2, v3);
    }
    // ---- softmax: row i=i0+lo lane-local; tree reduce + 2 shfl ----
#pragma unroll
    for (int t = 0; t < 4; ++t)
#pragma unroll
      for (int r = 0; r < 4; ++r)
        s[t][r] += bf2f(Sd[wid][lo][16 * t + 4 * lg + r - lo + 15]);
    const float m0t = fmaxf(fmaxf(s[0][0], s[0][1]), fmaxf(s[0][2], s[0][3]));
    const float m1t = fmaxf(fmaxf(s[1][0], s[1][1]), fmaxf(s[1][2], s[1][3]));
    const float m2t = fmaxf(fmaxf(s[2][0], s[2][1]), fmaxf(s[2][2], s[2][3]));
    const float m3t = fmaxf(fmaxf(s[3][0], s[3][1]), fmaxf(s[3][2], s[3][3]));
    float mt = fmaxf(fmaxf(m0t, m1t), fmaxf(m2t, m3t));
    mt = fmaxf(mt, __shfl_xor(mt, 16));
    mt = fmaxf(mt, __shfl_xor(mt, 32));
    const float mnew = fmaxf(mrun, mt);
    const float scale = ex2(mrun - mnew);
#pragma unroll
    for (int t = 0; t < 4; ++t)
#pragma unroll
      for (int r = 0; r < 4; ++r)
        s[t][r] = ex2(s[t][r] - mnew);
    const float r0t = (s[0][0] + s[0][1]) + (s[0][2] + s[0][3]);
    const float r1t = (s[1][0] + s[1][1]) + (s[1][2] + s[1][3]);
    const float r2t = (s[2][0] + s[2][1]) + (s[2][2] + s[2][3]);
    const float r3t = (s[3][0] + s[3][1]) + (s[3][2] + s[3][3]);
    float rsum = (r0t + r1t) + (r2t + r3t);
    rsum += __shfl_xor(rsum, 16);
    rsum += __shfl_xor(rsum, 32);
    lrun = lrun * scale + rsum;
    mrun = mnew;
#pragma unroll
    for (int u = 0; u < 4; ++u)
#pragma unroll
      for (int r = 0; r < 4; ++r) o[u][r] *= scale;
    // ---- P pack -> Ps (plain stride-72, R6 pattern), read as B-frag ----
#pragma unroll
    for (int t = 0; t < 4; ++t) {
      *(unsigned*)&Ps[wid][lo][16 * t + 4 * lg]     = pkbf(s[t][0], s[t][1]);
      *(unsigned*)&Ps[wid][lo][16 * t + 4 * lg + 2] = pkbf(s[t][2], s[t][3]);
    }
    const bf16x8 pa0 = *(const bf16x8*)&Ps[wid][lo][8 * lg];
    const bf16x8 pa1 = *(const bf16x8*)&Ps[wid][lo][32 + 8 * lg];
    // ---- PV swapped: o[u] accumulates O^T[d=16u+4lg+r][i=i0+lo] ----
#pragma unroll
    for (int u = 0; u < 4; ++u) {
      const bf16x8 vb0 = *(const bf16x8*)&Vt[swz(16 * u + lo, lg)];
      const bf16x8 vb1 = *(const bf16x8*)&Vt[swz(16 * u + lo, lg + 4)];
      o[u] = MFMA16(vb0, pa0, o[u]);
      o[u] = MFMA16(vb1, pa1, o[u]);
    }
    __syncthreads();  // protect Kt/Vt/Rt before next stage overwrites
  }
  // ---- partial outputs: contiguous d per lane -> float4 stores ----
  const int i = i0 + lo;
  const long obase = (((long)(bh * Q_ + i)) * NSPLIT + js) * DH_;
#pragma unroll
  for (int u = 0; u < 4; ++u)
    *(f32x4*)&po[obase + 16 * u + 4 * lg] = o[u];
  if (lg == 0)
    pml[((long)(bh * Q_ + i)) * NSPLIT + js] = make_float2(mrun, lrun);
}

// ---------------- combine partial softmax halves (log2 domain) -------------
__global__ __launch_bounds__(256) void combine_kernel(
    const float* __restrict__ po, const float2* __restrict__ pml,
    bf16* __restrict__ attnv) {
  const long gid = (long)blockIdx.x * 256 + threadIdx.x;  // B*H*Q*DH
  const int col = gid & 63;
  const long row = gid >> 6;  // bh*Q + i
  const float2 ml0 = pml[row * NSPLIT];
  const float2 ml1 = pml[row * NSPLIT + 1];
  const float m = fmaxf(ml0.x, ml1.x);
  const float w0 = ex2(ml0.x - m), w1 = ex2(ml1.x - m);
  const float num = po[(row * NSPLIT) * DH_ + col] * w0 +
                    po[(row * NSPLIT + 1) * DH_ + col] * w1;
  const float den = ml0.y * w0 + ml1.y * w1;
  const int b = (int)(row >> 14);
  const int h = (int)(row >> 10) & 15;
  const int i = (int)row & 1023;
  attnv[((long)(b * Q_ + i)) * D_ + h * DH_ + col] = f2bf(num / den);
}

// ---------------- host ----------------
extern "C" void kernel_launch(void* const* d_in, const int* in_sizes, int n_in,
                              void* d_out, int out_size, void* d_ws, size_t ws_size,
                              hipStream_t stream) {
  (void)in_sizes; (void)n_in; (void)out_size; (void)ws_size;
  const float* h_in  = (const float*)d_in[0];
  const float* mem_in= (const float*)d_in[1];
  const float* r_in  = (const float*)d_in[2];
  const float* Wq = (const float*)d_in[3];
  const float* Wk = (const float*)d_in[4];
  const float* Wv = (const float*)d_in[5];
  const float* Wr = (const float*)d_in[6];
  const float* Wo = (const float*)d_in[7];
  const float* rwb = (const float*)d_in[8];
  const float* rrb = (const float*)d_in[9];

  float* out = (float*)d_out;
  float* kcache = out + (long)B_ * Q_ * D_;
  float* vcache = kcache + (long)B_ * H_ * MEM_ * DH_;

  char* w = (char*)d_ws;
  auto alloc = [&](size_t bytes) {
    char* p = w;
    w += (bytes + 255) & ~(size_t)255;
    return p;
  };
  bf16* h_bf   = (bf16*)alloc((size_t)B_ * Q_ * D_ * 2);
  bf16* mem_bf = (bf16*)alloc((size_t)B_ * MEM_ * D_ * 2);
  bf16* r_bf   = (bf16*)alloc((size_t)KLEN_ * D_ * 2);
  bf16* Wqt = (bf16*)alloc((size_t)D_ * D_ * 2);
  bf16* Wkt = (bf16*)alloc((size_t)D_ * D_ * 2);
  bf16* Wvt = (bf16*)alloc((size_t)D_ * D_ * 2);
  bf16* Wrt = (bf16*)alloc((size_t)D_ * D_ * 2);
  bf16* Wot = (bf16*)alloc((size_t)D_ * D_ * 2);
  bf16* qw    = (bf16*)alloc((size_t)B_ * H_ * Q_ * DH_ * 2);
  bf16* qr    = (bf16*)alloc((size_t)B_ * H_ * Q_ * DH_ * 2);
  bf16* kall  = (bf16*)alloc((size_t)B_ * H_ * KLEN_ * DH_ * 2);
  bf16* vT    = (bf16*)alloc((size_t)B_ * H_ * KLEN_ * DH_ * 2);
  bf16* rhead = (bf16*)alloc((size_t)H_ * KLEN_ * DH_ * 2);
  bf16* attnv = (bf16*)alloc((size_t)B_ * Q_ * D_ * 2);
  float* po   = (float*)alloc((size_t)B_ * H_ * Q_ * NSPLIT * DH_ * 4);
  float2* pml = (float2*)alloc((size_t)B_ * H_ * Q_ * NSPLIT * 8);

  // 1. f32 -> bf16 conversions
  CvtArgs ca;
  ca.src[0] = h_in;   ca.dst[0] = h_bf;   ca.n4[0] = B_ * Q_ * D_ / 4;
  ca.src[1] = mem_in; ca.dst[1] = mem_bf; ca.n4[1] = B_ * MEM_ * D_ / 4;
  ca.src[2] = r_in;   ca.dst[2] = r_bf;   ca.n4[2] = KLEN_ * D_ / 4;
  cvt_kernel<<<dim3((B_ * Q_ * D_ / 4 + 255) / 256, 1, 3), 256, 0, stream>>>(ca);

  // 2. weight transposes
  TpArgs ta;
  ta.w[0] = Wq; ta.o[0] = Wqt;
  ta.w[1] = Wk; ta.o[1] = Wkt;
  ta.w[2] = Wv; ta.o[2] = Wvt;
  ta.w[3] = Wr; ta.o[3] = Wrt;
  ta.w[4] = Wo; ta.o[4] = Wot;
  tp_kernel<<<dim3(32, 32, 5), dim3(32, 8), 0, stream>>>(ta);

  GemmArgs g{};
  g.qw = qw; g.qr = qr; g.kall = kall; g.vT = vT; g.rhead = rhead;
  g.kcache = kcache; g.vcache = vcache; g.fout = out; g.rwb = rwb; g.rrb = rrb;

  // 3. h @ [Wq|Wk|Wv]  (M=4096, N=3072, K=1024)
  g.A = h_bf; g.Bt = Wqt; g.K = D_; g.batchA = 0; g.batchB = 0;
  gemm_bt<EPI_HQKV><<<dim3(3 * D_ / 128, B_ * Q_ / 128, 1), 256, 0, stream>>>(g);

  // 4. mem @ [Wk|Wv]  (M=4096, N=2048, K=1024)
  g.A = mem_bf; g.Bt = Wkt;
  gemm_bt<EPI_MEMKV><<<dim3(2 * D_ / 128, B_ * MEM_ / 128, 1), 256, 0, stream>>>(g);

  // 5. r @ Wr  (M=2048, N=1024, K=1024)
  g.A = r_bf; g.Bt = Wrt;
  gemm_bt<EPI_R><<<dim3(D_ / 128, KLEN_ / 128, 1), 256, 0, stream>>>(g);

  // 6. fused attention (KV-split, XCD-swizzled, swapped-operand) + combine
  attn_kernel<<<dim3(Q_ / 64 * H_ * B_ * NSPLIT), 256, 0, stream>>>(
      qw, qr, kall, vT, rhead, po, pml);
  combine_kernel<<<dim3(B_ * H_ * Q_ * DH_ / 256), 256, 0, stream>>>(po, pml, attnv);

  // 7. out = attnv @ Wo  (M=4096, N=1024, K=1024)
  g.A = attnv; g.Bt = Wot; g.K = D_; g.batchA = 0; g.batchB = 0;
  gemm_bt<EPI_OUT><<<dim3(D_ / 128, B_ * Q_ / 128, 1), 256, 0, stream>>>(g);
}

// Round 12
// 378.066 us; speedup vs baseline: 1.1394x; 1.0529x over previous
//
#include <hip/hip_runtime.h>
#include <hip/hip_bf16.h>

#define B_ 4
#define Q_ 1024
#define MEM_ 1024
#define D_ 1024
#define H_ 16
#define DH_ 64
#define KLEN_ 2048
#define NSPLIT 2

typedef __hip_bfloat16 bf16;
typedef __bf16 bf16x8 __attribute__((ext_vector_type(8)));
typedef float f32x4 __attribute__((ext_vector_type(4)));

__device__ __forceinline__ float bf2f(bf16 x) { return __bfloat162float(x); }
__device__ __forceinline__ bf16 f2bf(float x) { return __float2bfloat16(x); }

// 2^x via v_exp_f32 (NOT __exp2f: glibc math.h macro collision, R7 lesson)
__device__ __forceinline__ float ex2(float x) { return __builtin_amdgcn_exp2f(x); }

// pack 2 f32 -> dword of 2 bf16 (no builtin on gfx950; T12 recipe)
__device__ __forceinline__ unsigned pkbf(float a, float b) {
  unsigned d;
  asm volatile("v_cvt_pk_bf16_f32 %0, %1, %2" : "=v"(d) : "v"(a), "v"(b));
  return d;
}

__device__ __forceinline__ unsigned short f2bf_bits(float x) {
  union { float f; unsigned u; } a; a.f = x;
  unsigned u = a.u;
  unsigned r = u + 0x7FFFu + ((u >> 16) & 1u);
  return (unsigned short)(r >> 16);
}

#define MFMA16(a, b, c) __builtin_amdgcn_mfma_f32_16x16x32_bf16((a), (b), (c), 0, 0, 0)
#define GLDS(gsrc, ldst) __builtin_amdgcn_global_load_lds( \
    (const __attribute__((address_space(1))) void*)(gsrc), \
    (__attribute__((address_space(3))) void*)(ldst), 16, 0, 0)

// swizzled LDS address for a 16B chunk: rows of 64 bf16 (128B = 8 chunks),
// chunk slot XORed with row&7 so column-slice b128 reads spread across banks
__device__ __forceinline__ int swz(int row, int ch) {
  return row * 64 + ((ch ^ (row & 7)) * 8);
}

// 0.125 (1/sqrt(DH)) * log2(e): scores land in log2 domain -> exp2 softmax
#define QSCALE 0.180336880111112f

// ---------------- conversions ----------------
struct CvtArgs { const float* src[3]; bf16* dst[3]; int n4[3]; };

__global__ void cvt_kernel(CvtArgs a) {
  const int z = blockIdx.z;
  const float4* s = (const float4*)a.src[z];
  const int n4 = a.n4[z];
  const int i = blockIdx.x * blockDim.x + threadIdx.x;
  if (i < n4) {
    float4 v = s[i];
    ushort4 o;
    o.x = f2bf_bits(v.x); o.y = f2bf_bits(v.y);
    o.z = f2bf_bits(v.z); o.w = f2bf_bits(v.w);
    ((ushort4*)a.dst[z])[i] = o;
  }
}

// ---------------- weight transpose (f32 -> bf16, Wt[n][k] = W[k][n]) -------
struct TpArgs { const float* w[5]; bf16* o[5]; };

__global__ void tp_kernel(TpArgs a) {
  __shared__ float t[32][33];
  const int z = blockIdx.z;
  const float* W = a.w[z];
  bf16* Wt = a.o[z];
  const int bx = blockIdx.x * 32, by = blockIdx.y * 32;
  const int tx = threadIdx.x, ty = threadIdx.y;
#pragma unroll
  for (int y = ty; y < 32; y += 8) t[y][tx] = W[(long)(by + y) * D_ + bx + tx];
  __syncthreads();
#pragma unroll
  for (int y = ty; y < 32; y += 8)
    Wt[(long)(bx + y) * D_ + by + tx] = f2bf(t[tx][y]);
}

// ---------------- fused GEMM (A row-major MxK bf16, Bt row-major NxK) ------
// BK=64, T2 chunk-XOR swizzle on As/Bs (rule #21: linear GLDS dest +
// inverse-swizzled global source + swizzled fragment read -> 2-way conflicts,
// free), 32 MFMA per barrier pair (halved barrier drains vs BK=32).
// which==0: one 1408-wg dispatch covering {h@Wqkv | mem@Wkv | r@Wr};
// which==1: 256-wg out = attnv@Wo. Both XCD-chunk-swizzled (bijective).
struct GemmArgs {
  const bf16 *h_bf, *mem_bf, *r_bf, *attnv;
  const bf16 *Wqt, *Wkt, *Wrt, *Wot;
  bf16 *qw, *qr, *kall, *vT, *rhead;
  float *kcache, *vcache, *fout;
  const float *rwb, *rrb;
};

__global__ __launch_bounds__(256) void gemm_fused(GemmArgs g, int which) {
  __shared__ bf16 As[128 * 64];
  __shared__ bf16 Bs[128 * 64];
  const int tid = threadIdx.x;
  const int wid = tid >> 6, lane = tid & 63;
  const int wr = wid >> 1, wc = wid & 1;
  const int lo = lane & 15, lg = lane >> 4;

  const bf16 *A, *Bt;
  int m0, n0, mode;
  if (which == 0) {
    const int hw = blockIdx.x;               // 1408 = 8 XCDs x 176
    const int wg = (hw & 7) * 176 + (hw >> 3);
    if (wg < 768)       { mode = 0; A = g.h_bf;   Bt = g.Wqt; const int l = wg;        m0 = (l / 24) * 128; n0 = (l % 24) * 128; }
    else if (wg < 1280) { mode = 1; A = g.mem_bf; Bt = g.Wkt; const int l = wg - 768;  m0 = (l / 16) * 128; n0 = (l % 16) * 128; }
    else                { mode = 2; A = g.r_bf;   Bt = g.Wrt; const int l = wg - 1280; m0 = (l / 8) * 128;  n0 = (l % 8) * 128; }
  } else {
    const int hw = blockIdx.x;               // 256 = 8 x 32
    const int wg = (hw & 7) * 32 + (hw >> 3);
    mode = 3; A = g.attnv; Bt = g.Wot; m0 = (wg / 8) * 128; n0 = (wg % 8) * 128;
  }

  f32x4 acc[4][4] = {};

  for (int kt = 0; kt < D_; kt += 64) {
#pragma unroll
    for (int s = 0; s < 4; ++s) {
      const int c = tid + s * 256, row = c >> 3, gch = (c & 7) ^ (row & 7);
      GLDS(A + (long)(m0 + row) * D_ + kt + gch * 8, &As[c * 8]);
    }
#pragma unroll
    for (int s = 0; s < 4; ++s) {
      const int c = tid + s * 256, row = c >> 3, gch = (c & 7) ^ (row & 7);
      GLDS(Bt + (long)(n0 + row) * D_ + kt + gch * 8, &Bs[c * 8]);
    }
    __syncthreads();
#pragma unroll
    for (int kk = 0; kk < 2; ++kk) {
      bf16x8 af[4], bfv[4];
#pragma unroll
      for (int m = 0; m < 4; ++m) {
        const int r_ = 64 * wr + 16 * m + lo;
        af[m] = *(const bf16x8*)&As[r_ * 64 + (((kk * 4 + lg) ^ (r_ & 7)) * 8)];
      }
#pragma unroll
      for (int n = 0; n < 4; ++n) {
        const int r_ = 64 * wc + 16 * n + lo;
        bfv[n] = *(const bf16x8*)&Bs[r_ * 64 + (((kk * 4 + lg) ^ (r_ & 7)) * 8)];
      }
#pragma unroll
      for (int m = 0; m < 4; ++m)
#pragma unroll
        for (int n = 0; n < 4; ++n)
          acc[m][n] = MFMA16(af[m], bfv[n], acc[m][n]);
    }
    __syncthreads();
  }

  // ---- epilogues (wave-uniform mode; separate loops keep codegen clean) ----
  if (mode == 0) {
#pragma unroll
    for (int m = 0; m < 4; ++m)
#pragma unroll
      for (int n = 0; n < 4; ++n)
#pragma unroll
        for (int r = 0; r < 4; ++r) {
          const float v = acc[m][n][r];
          const int gr = m0 + 64 * wr + 16 * m + lg * 4 + r;
          const int gc = n0 + 64 * wc + 16 * n + lo;
          const int b = gr >> 10, i = gr & 1023;
          const int seg = gc >> 10, c = gc & 1023;
          const int hh = c >> 6, dh = c & 63;
          const long bh = (long)(b * H_ + hh);
          if (seg == 0) {
            const long idx = (bh * Q_ + i) * DH_ + dh;
            g.qw[idx] = f2bf((v + g.rwb[c]) * QSCALE);
            g.qr[idx] = f2bf((v + g.rrb[c]) * QSCALE);
          } else if (seg == 1) {
            g.kall[(bh * KLEN_ + MEM_ + i) * DH_ + dh] = f2bf(v);
            g.kcache[(bh * MEM_ + i) * DH_ + dh] = v;
          } else {
            g.vT[(bh * DH_ + dh) * KLEN_ + MEM_ + i] = f2bf(v);
            g.vcache[(bh * MEM_ + i) * DH_ + dh] = v;
          }
        }
  } else if (mode == 1) {
#pragma unroll
    for (int m = 0; m < 4; ++m)
#pragma unroll
      for (int n = 0; n < 4; ++n)
#pragma unroll
        for (int r = 0; r < 4; ++r) {
          const float v = acc[m][n][r];
          const int gr = m0 + 64 * wr + 16 * m + lg * 4 + r;
          const int gc = n0 + 64 * wc + 16 * n + lo;
          const int b = gr >> 10, i = gr & 1023;
          const int seg = gc >> 10, c = gc & 1023;
          const int hh = c >> 6, dh = c & 63;
          const long bh = (long)(b * H_ + hh);
          if (seg == 0) g.kall[(bh * KLEN_ + i) * DH_ + dh] = f2bf(v);
          else          g.vT[(bh * DH_ + dh) * KLEN_ + i] = f2bf(v);
        }
  } else if (mode == 2) {
#pragma unroll
    for (int m = 0; m < 4; ++m)
#pragma unroll
      for (int n = 0; n < 4; ++n)
#pragma unroll
        for (int r = 0; r < 4; ++r) {
          const float v = acc[m][n][r];
          const int gr = m0 + 64 * wr + 16 * m + lg * 4 + r;
          const int gc = n0 + 64 * wc + 16 * n + lo;
          const int hh = gc >> 6, dh = gc & 63;
          g.rhead[((long)hh * KLEN_ + gr) * DH_ + dh] = f2bf(v);
        }
  } else {
#pragma unroll
    for (int m = 0; m < 4; ++m)
#pragma unroll
      for (int n = 0; n < 4; ++n)
#pragma unroll
        for (int r = 0; r < 4; ++r) {
          const int gr = m0 + 64 * wr + 16 * m + lg * 4 + r;
          const int gc = n0 + 64 * wc + 16 * n + lo;
          g.fout[(long)gr * D_ + gc] = acc[m][n][r];
        }
  }
}

// ---------------- fused attention: swapped-operand S^T form (R11) ----------
__global__ __launch_bounds__(256) void attn_kernel(
    const bf16* __restrict__ qw, const bf16* __restrict__ qr,
    const bf16* __restrict__ kall, const bf16* __restrict__ vT,
    const bf16* __restrict__ rhead, float* __restrict__ po,
    float2* __restrict__ pml) {
  __shared__ bf16 Kt[64 * 64];
  __shared__ bf16 Vt[64 * 64];
  __shared__ bf16 Rt[128 * 64];
  __shared__ bf16 Sd[4][16][86];  // [wave][i-row][band col], stride 86
  __shared__ bf16 Ps[4][16][72];  // [wave][i-row][j col], stride 72
  const int hw = blockIdx.x;
  const int L = ((hw & 7) << 8) | (hw >> 3);
  const int xb = L & 15;
  const int h = (L >> 4) & 15;
  const int js = (L >> 8) & 1;
  const int b = L >> 9;
  const int tid = threadIdx.x;
  const int wid = tid >> 6, lane = tid & 63;
  const int lo = lane & 15, lg = lane >> 4;
  const int I0 = xb * 64;
  const int i0 = I0 + wid * 16;
  const long bh = (long)(b * H_ + h);
  const bf16* rh = rhead + (long)h * KLEN_ * DH_;
  const bf16* kbase = kall + bh * KLEN_ * DH_;
  const bf16* vbase = vT + bh * DH_ * KLEN_;

  const bf16x8 aq0 = *(const bf16x8*)&qw[(bh * Q_ + i0 + lo) * DH_ + lg * 8];
  const bf16x8 aq1 = *(const bf16x8*)&qw[(bh * Q_ + i0 + lo) * DH_ + 32 + lg * 8];
  const bf16x8 ar0 = *(const bf16x8*)&qr[(bh * Q_ + i0 + lo) * DH_ + lg * 8];
  const bf16x8 ar1 = *(const bf16x8*)&qr[(bh * Q_ + i0 + lo) * DH_ + 32 + lg * 8];

  f32x4 o[4] = {};
  float mrun = -1e30f, lrun = 0.f;  // lane-local: one q-row per lane

  const int jbeg = js << 10, jend = jbeg + (KLEN_ / NSPLIT);
  for (int j0 = jbeg; j0 < jend; j0 += 64) {
    const int d0 = j0 - I0 - 63;  // Rt[row] = rhead[m(d0+row)]
#pragma unroll
    for (int ss = 0; ss < 2; ++ss) {
      const int c = tid + ss * 256;
      const int row = c >> 3;
      const int gch = (c & 7) ^ (row & 7);
      GLDS(kbase + (long)(j0 + row) * DH_ + gch * 8, &Kt[c * 8]);
    }
#pragma unroll
    for (int ss = 0; ss < 2; ++ss) {
      const int c = tid + ss * 256;
      const int row = c >> 3;
      const int gch = (c & 7) ^ (row & 7);
      GLDS(vbase + (long)row * KLEN_ + j0 + gch * 8, &Vt[c * 8]);
    }
#pragma unroll
    for (int ss = 0; ss < 4; ++ss) {
      const int c = tid + ss * 256;
      const int row = c >> 3;
      const int dcol = d0 + row;
      int m = dcol + ((dcol >= 1026) ? -1026 : 1023);
      m = max(0, min(m, KLEN_ - 1));
      const int gch = (c & 7) ^ (row & 7);
      GLDS(rh + (long)m * DH_ + gch * 8, &Rt[c * 8]);
    }
    __syncthreads();

    // ---- QK^T swapped: s[t][r] = S[i=i0+lo][j=j0+16t+4lg+r] ----
    f32x4 s[4];
#pragma unroll
    for (int t = 0; t < 4; ++t) {
      const bf16x8 kb0 = *(const bf16x8*)&Kt[swz(16 * t + lo, lg)];
      const bf16x8 kb1 = *(const bf16x8*)&Kt[swz(16 * t + lo, lg + 4)];
      f32x4 z = {};
      z = MFMA16(kb0, aq0, z);
      z = MFMA16(kb1, aq1, z);
      s[t] = z;
    }
    // ---- BD swapped: D[c][i]; lane holds c=crow0+16t+4lg+r, i=i0+lo ----
    const int crow0 = 48 - 16 * wid;
#pragma unroll
    for (int t = 0; t < 5; ++t) {
      const int dtb = d0 + crow0 + 16 * t;
      const bool need1 = (dtb <= 1024);
      const bool need2 = (dtb + 15 >= 1026);
      const int c = crow0 + 16 * t + lo;
      const bf16x8 rb0 = *(const bf16x8*)&Rt[swz(c, lg)];
      const bf16x8 rb1 = *(const bf16x8*)&Rt[swz(c, lg + 4)];
      f32x4 z1 = {}, z2 = {};
      if (need1) { z1 = MFMA16(rb0, ar0, z1); z1 = MFMA16(rb1, ar1, z1); }
      if (need2) {
        const int rs = min(i0 + 1 + lo, Q_ - 1);
        const bf16x8 as0 = *(const bf16x8*)&qr[(bh * Q_ + rs) * DH_ + lg * 8];
        const bf16x8 as1 = *(const bf16x8*)&qr[(bh * Q_ + rs) * DH_ + 32 + lg * 8];
        z2 = MFMA16(rb0, as0, z2);
        z2 = MFMA16(rb1, as1, z2);
      }
      float v0, v1, v2, v3;
      {
        const int dlt0 = dtb + 4 * lg;
        v0 = (dlt0 + 0 >= 1026) ? z2[0] : z1[0]; if (dlt0 + 0 == 1025) v0 = 0.f;
        v1 = (dlt0 + 1 >= 1026) ? z2[1] : z1[1]; if (dlt0 + 1 == 1025) v1 = 0.f;
        v2 = (dlt0 + 2 >= 1026) ? z2[2] : z1[2]; if (dlt0 + 2 == 1025) v2 = 0.f;
        v3 = (dlt0 + 3 >= 1026) ? z2[3] : z1[3]; if (dlt0 + 3 == 1025) v3 = 0.f;
      }
      *(unsigned*)&Sd[wid][lo][16 * t + 4 * lg]     = pkbf(v0, v1);
      *(unsigned*)&Sd[wid][lo][16 * t + 4 * lg + 2] = pkbf(v2, v3);
    }
    // ---- softmax: row i=i0+lo lane-local; tree reduce + 2 shfl ----
#pragma unroll
    for (int t = 0; t < 4; ++t)
#pragma unroll
      for (int r = 0; r < 4; ++r)
        s[t][r] += bf2f(Sd[wid][lo][16 * t + 4 * lg + r - lo + 15]);
    const float m0t = fmaxf(fmaxf(s[0][0], s[0][1]), fmaxf(s[0][2], s[0][3]));
    const float m1t = fmaxf(fmaxf(s[1][0], s[1][1]), fmaxf(s[1][2], s[1][3]));
    const float m2t = fmaxf(fmaxf(s[2][0], s[2][1]), fmaxf(s[2][2], s[2][3]));
    const float m3t = fmaxf(fmaxf(s[3][0], s[3][1]), fmaxf(s[3][2], s[3][3]));
    float mt = fmaxf(fmaxf(m0t, m1t), fmaxf(m2t, m3t));
    mt = fmaxf(mt, __shfl_xor(mt, 16));
    mt = fmaxf(mt, __shfl_xor(mt, 32));
    const float mnew = fmaxf(mrun, mt);
    const float scale = ex2(mrun - mnew);
#pragma unroll
    for (int t = 0; t < 4; ++t)
#pragma unroll
      for (int r = 0; r < 4; ++r)
        s[t][r] = ex2(s[t][r] - mnew);
    const float r0t = (s[0][0] + s[0][1]) + (s[0][2] + s[0][3]);
    const float r1t = (s[1][0] + s[1][1]) + (s[1][2] + s[1][3]);
    const float r2t = (s[2][0] + s[2][1]) + (s[2][2] + s[2][3]);
    const float r3t = (s[3][0] + s[3][1]) + (s[3][2] + s[3][3]);
    float rsum = (r0t + r1t) + (r2t + r3t);
    rsum += __shfl_xor(rsum, 16);
    rsum += __shfl_xor(rsum, 32);
    lrun = lrun * scale + rsum;
    mrun = mnew;
#pragma unroll
    for (int u = 0; u < 4; ++u)
#pragma unroll
      for (int r = 0; r < 4; ++r) o[u][r] *= scale;
    // ---- P pack -> Ps (plain stride-72), read as B-frag ----
#pragma unroll
    for (int t = 0; t < 4; ++t) {
      *(unsigned*)&Ps[wid][lo][16 * t + 4 * lg]     = pkbf(s[t][0], s[t][1]);
      *(unsigned*)&Ps[wid][lo][16 * t + 4 * lg + 2] = pkbf(s[t][2], s[t][3]);
    }
    const bf16x8 pa0 = *(const bf16x8*)&Ps[wid][lo][8 * lg];
    const bf16x8 pa1 = *(const bf16x8*)&Ps[wid][lo][32 + 8 * lg];
    // ---- PV swapped: o[u] accumulates O^T[d=16u+4lg+r][i=i0+lo] ----
#pragma unroll
    for (int u = 0; u < 4; ++u) {
      const bf16x8 vb0 = *(const bf16x8*)&Vt[swz(16 * u + lo, lg)];
      const bf16x8 vb1 = *(const bf16x8*)&Vt[swz(16 * u + lo, lg + 4)];
      o[u] = MFMA16(vb0, pa0, o[u]);
      o[u] = MFMA16(vb1, pa1, o[u]);
    }
    __syncthreads();
  }
  // ---- partial outputs: contiguous d per lane -> float4 stores ----
  const int i = i0 + lo;
  const long obase = (((long)(bh * Q_ + i)) * NSPLIT + js) * DH_;
#pragma unroll
  for (int u = 0; u < 4; ++u)
    *(f32x4*)&po[obase + 16 * u + 4 * lg] = o[u];
  if (lg == 0)
    pml[((long)(bh * Q_ + i)) * NSPLIT + js] = make_float2(mrun, lrun);
}

// ---------------- combine partial softmax halves (log2 domain) -------------
__global__ __launch_bounds__(256) void combine_kernel(
    const float* __restrict__ po, const float2* __restrict__ pml,
    bf16* __restrict__ attnv) {
  const long gid = (long)blockIdx.x * 256 + threadIdx.x;  // B*H*Q*DH
  const int col = gid & 63;
  const long row = gid >> 6;  // bh*Q + i
  const float2 ml0 = pml[row * NSPLIT];
  const float2 ml1 = pml[row * NSPLIT + 1];
  const float m = fmaxf(ml0.x, ml1.x);
  const float w0 = ex2(ml0.x - m), w1 = ex2(ml1.x - m);
  const float num = po[(row * NSPLIT) * DH_ + col] * w0 +
                    po[(row * NSPLIT + 1) * DH_ + col] * w1;
  const float den = ml0.y * w0 + ml1.y * w1;
  const int b = (int)(row >> 14);
  const int h = (int)(row >> 10) & 15;
  const int i = (int)row & 1023;
  attnv[((long)(b * Q_ + i)) * D_ + h * DH_ + col] = f2bf(num / den);
}

// ---------------- host ----------------
extern "C" void kernel_launch(void* const* d_in, const int* in_sizes, int n_in,
                              void* d_out, int out_size, void* d_ws, size_t ws_size,
                              hipStream_t stream) {
  (void)in_sizes; (void)n_in; (void)out_size; (void)ws_size;
  const float* h_in  = (const float*)d_in[0];
  const float* mem_in= (const float*)d_in[1];
  const float* r_in  = (const float*)d_in[2];
  const float* Wq = (const float*)d_in[3];
  const float* Wk = (const float*)d_in[4];
  const float* Wv = (const float*)d_in[5];
  const float* Wr = (const float*)d_in[6];
  const float* Wo = (const float*)d_in[7];
  const float* rwb = (const float*)d_in[8];
  const float* rrb = (const float*)d_in[9];

  float* out = (float*)d_out;
  float* kcache = out + (long)B_ * Q_ * D_;
  float* vcache = kcache + (long)B_ * H_ * MEM_ * DH_;

  char* w = (char*)d_ws;
  auto alloc = [&](size_t bytes) {
    char* p = w;
    w += (bytes + 255) & ~(size_t)255;
    return p;
  };
  bf16* h_bf   = (bf16*)alloc((size_t)B_ * Q_ * D_ * 2);
  bf16* mem_bf = (bf16*)alloc((size_t)B_ * MEM_ * D_ * 2);
  bf16* r_bf   = (bf16*)alloc((size_t)KLEN_ * D_ * 2);
  bf16* Wqt = (bf16*)alloc((size_t)D_ * D_ * 2);   // NOTE: Wqt/Wkt/Wvt
  bf16* Wkt = (bf16*)alloc((size_t)D_ * D_ * 2);   // contiguous (2MB each,
  bf16* Wvt = (bf16*)alloc((size_t)D_ * D_ * 2);   // 256-aligned) -- HQKV
  bf16* Wrt = (bf16*)alloc((size_t)D_ * D_ * 2);   // gemm spans them as N=3072
  bf16* Wot = (bf16*)alloc((size_t)D_ * D_ * 2);
  bf16* qw    = (bf16*)alloc((size_t)B_ * H_ * Q_ * DH_ * 2);
  bf16* qr    = (bf16*)alloc((size_t)B_ * H_ * Q_ * DH_ * 2);
  bf16* kall  = (bf16*)alloc((size_t)B_ * H_ * KLEN_ * DH_ * 2);
  bf16* vT    = (bf16*)alloc((size_t)B_ * H_ * KLEN_ * DH_ * 2);
  bf16* rhead = (bf16*)alloc((size_t)H_ * KLEN_ * DH_ * 2);
  bf16* attnv = (bf16*)alloc((size_t)B_ * Q_ * D_ * 2);
  float* po   = (float*)alloc((size_t)B_ * H_ * Q_ * NSPLIT * DH_ * 4);
  float2* pml = (float2*)alloc((size_t)B_ * H_ * Q_ * NSPLIT * 8);

  // 1. f32 -> bf16 conversions
  CvtArgs ca;
  ca.src[0] = h_in;   ca.dst[0] = h_bf;   ca.n4[0] = B_ * Q_ * D_ / 4;
  ca.src[1] = mem_in; ca.dst[1] = mem_bf; ca.n4[1] = B_ * MEM_ * D_ / 4;
  ca.src[2] = r_in;   ca.dst[2] = r_bf;   ca.n4[2] = KLEN_ * D_ / 4;
  cvt_kernel<<<dim3((B_ * Q_ * D_ / 4 + 255) / 256, 1, 3), 256, 0, stream>>>(ca);

  // 2. weight transposes
  TpArgs ta;
  ta.w[0] = Wq; ta.o[0] = Wqt;
  ta.w[1] = Wk; ta.o[1] = Wkt;
  ta.w[2] = Wv; ta.o[2] = Wvt;
  ta.w[3] = Wr; ta.o[3] = Wrt;
  ta.w[4] = Wo; ta.o[4] = Wot;
  tp_kernel<<<dim3(32, 32, 5), dim3(32, 8), 0, stream>>>(ta);

  GemmArgs g{};
  g.h_bf = h_bf; g.mem_bf = mem_bf; g.r_bf = r_bf; g.attnv = attnv;
  g.Wqt = Wqt; g.Wkt = Wkt; g.Wrt = Wrt; g.Wot = Wot;
  g.qw = qw; g.qr = qr; g.kall = kall; g.vT = vT; g.rhead = rhead;
  g.kcache = kcache; g.vcache = vcache; g.fout = out; g.rwb = rwb; g.rrb = rrb;

  // 3. fused projections: {h@[Wq|Wk|Wv] (768 wgs), mem@[Wk|Wv] (512), r@Wr (128)}
  gemm_fused<<<dim3(1408), 256, 0, stream>>>(g, 0);

  // 4. fused attention (KV-split, XCD-swizzled, swapped-operand) + combine
  attn_kernel<<<dim3(Q_ / 64 * H_ * B_ * NSPLIT), 256, 0, stream>>>(
      qw, qr, kall, vT, rhead, po, pml);
  combine_kernel<<<dim3(B_ * H_ * Q_ * DH_ / 256), 256, 0, stream>>>(po, pml, attnv);

  // 5. out = attnv @ Wo  (M=4096, N=1024, K=1024)
  gemm_fused<<<dim3(256), 256, 0, stream>>>(g, 1);
}

// Round 13
// 362.157 us; speedup vs baseline: 1.1894x; 1.0439x over previous
//
#include <hip/hip_runtime.h>
#include <hip/hip_bf16.h>

#define B_ 4
#define Q_ 1024
#define MEM_ 1024
#define D_ 1024
#define H_ 16
#define DH_ 64
#define KLEN_ 2048
#define NSPLIT 2

typedef __hip_bfloat16 bf16;
typedef __bf16 bf16x8 __attribute__((ext_vector_type(8)));
typedef float f32x4 __attribute__((ext_vector_type(4)));

__device__ __forceinline__ float bf2f(bf16 x) { return __bfloat162float(x); }
__device__ __forceinline__ bf16 f2bf(float x) { return __float2bfloat16(x); }

// 2^x via v_exp_f32 (NOT __exp2f: glibc math.h macro collision, R7 lesson)
__device__ __forceinline__ float ex2(float x) { return __builtin_amdgcn_exp2f(x); }

// pack 2 f32 -> dword of 2 bf16, low=a high=b (no builtin on gfx950)
__device__ __forceinline__ unsigned pkbf(float a, float b) {
  unsigned d;
  asm volatile("v_cvt_pk_bf16_f32 %0, %1, %2" : "=v"(d) : "v"(a), "v"(b));
  return d;
}

__device__ __forceinline__ unsigned short f2bf_bits(float x) {
  union { float f; unsigned u; } a; a.f = x;
  unsigned u = a.u;
  unsigned r = u + 0x7FFFu + ((u >> 16) & 1u);
  return (unsigned short)(r >> 16);
}

#define MFMA16(a, b, c) __builtin_amdgcn_mfma_f32_16x16x32_bf16((a), (b), (c), 0, 0, 0)
#define GLDS(gsrc, ldst) __builtin_amdgcn_global_load_lds( \
    (const __attribute__((address_space(1))) void*)(gsrc), \
    (__attribute__((address_space(3))) void*)(ldst), 16, 0, 0)

// swizzled LDS address for a 16B chunk: rows of 64 bf16 (128B = 8 chunks),
// chunk slot XORed with row&7 so column-slice b128 reads spread across banks
__device__ __forceinline__ int swz(int row, int ch) {
  return row * 64 + ((ch ^ (row & 7)) * 8);
}

// 0.125 (1/sqrt(DH)) * log2(e): scores land in log2 domain -> exp2 softmax
#define QSCALE 0.180336880111112f

// ---------------- conversions ----------------
struct CvtArgs { const float* src[3]; bf16* dst[3]; int n4[3]; };

__global__ void cvt_kernel(CvtArgs a) {
  const int z = blockIdx.z;
  const float4* s = (const float4*)a.src[z];
  const int n4 = a.n4[z];
  const int i = blockIdx.x * blockDim.x + threadIdx.x;
  if (i < n4) {
    float4 v = s[i];
    ushort4 o;
    o.x = f2bf_bits(v.x); o.y = f2bf_bits(v.y);
    o.z = f2bf_bits(v.z); o.w = f2bf_bits(v.w);
    ((ushort4*)a.dst[z])[i] = o;
  }
}

// ---------------- weight transpose (f32 -> bf16, Wt[n][k] = W[k][n]) -------
struct TpArgs { const float* w[5]; bf16* o[5]; };

__global__ void tp_kernel(TpArgs a) {
  __shared__ float t[32][33];
  const int z = blockIdx.z;
  const float* W = a.w[z];
  bf16* Wt = a.o[z];
  const int bx = blockIdx.x * 32, by = blockIdx.y * 32;
  const int tx = threadIdx.x, ty = threadIdx.y;
#pragma unroll
  for (int y = ty; y < 32; y += 8) t[y][tx] = W[(long)(by + y) * D_ + bx + tx];
  __syncthreads();
#pragma unroll
  for (int y = ty; y < 32; y += 8)
    Wt[(long)(bx + y) * D_ + by + tx] = f2bf(t[tx][y]);
}

// ---------------- fused GEMM (A row-major MxK bf16, Bt row-major NxK) ------
// BK=64, chunk-XOR swizzle on As/Bs. vT-producing blocks (mode0 seg2, mode1
// seg1) stage their tile through a 32KB LDS dword-transpose (reusing the dead
// As/Bs after the K-loop) so vT stores become coalesced uint4 writes instead
// of 2B stores at 4KB stride (R12 diagnosis: scattered-store epilogue).
struct GemmArgs {
  const bf16 *h_bf, *mem_bf, *r_bf, *attnv;
  const bf16 *Wqt, *Wkt, *Wrt, *Wot;
  bf16 *qw, *qr, *kall, *vT, *rhead;
  float *kcache, *vcache, *fout;
  const float *rwb, *rrb;
};

__global__ __launch_bounds__(256) void gemm_fused(GemmArgs g, int which) {
  __shared__ __align__(16) char shraw[32768];  // As(16K) | Bs(16K), reused as tr
  bf16* As = (bf16*)shraw;
  bf16* Bs = (bf16*)(shraw + 16384);
  const int tid = threadIdx.x;
  const int wid = tid >> 6, lane = tid & 63;
  const int wr = wid >> 1, wc = wid & 1;
  const int lo = lane & 15, lg = lane >> 4;

  const bf16 *A, *Bt;
  int m0, n0, mode;
  if (which == 0) {
    const int hw = blockIdx.x;               // 1408 = 8 XCDs x 176
    const int wg = (hw & 7) * 176 + (hw >> 3);
    if (wg < 768)       { mode = 0; A = g.h_bf;   Bt = g.Wqt; const int l = wg;        m0 = (l / 24) * 128; n0 = (l % 24) * 128; }
    else if (wg < 1280) { mode = 1; A = g.mem_bf; Bt = g.Wkt; const int l = wg - 768;  m0 = (l / 16) * 128; n0 = (l % 16) * 128; }
    else                { mode = 2; A = g.r_bf;   Bt = g.Wrt; const int l = wg - 1280; m0 = (l / 8) * 128;  n0 = (l % 8) * 128; }
  } else {
    const int hw = blockIdx.x;               // 256 = 8 x 32
    const int wg = (hw & 7) * 32 + (hw >> 3);
    mode = 3; A = g.attnv; Bt = g.Wot; m0 = (wg / 8) * 128; n0 = (wg % 8) * 128;
  }

  f32x4 acc[4][4] = {};

  for (int kt = 0; kt < D_; kt += 64) {
#pragma unroll
    for (int s = 0; s < 4; ++s) {
      const int c = tid + s * 256, row = c >> 3, gch = (c & 7) ^ (row & 7);
      GLDS(A + (long)(m0 + row) * D_ + kt + gch * 8, &As[c * 8]);
    }
#pragma unroll
    for (int s = 0; s < 4; ++s) {
      const int c = tid + s * 256, row = c >> 3, gch = (c & 7) ^ (row & 7);
      GLDS(Bt + (long)(n0 + row) * D_ + kt + gch * 8, &Bs[c * 8]);
    }
    __syncthreads();
#pragma unroll
    for (int kk = 0; kk < 2; ++kk) {
      bf16x8 af[4], bfv[4];
#pragma unroll
      for (int m = 0; m < 4; ++m) {
        const int r_ = 64 * wr + 16 * m + lo;
        af[m] = *(const bf16x8*)&As[r_ * 64 + (((kk * 4 + lg) ^ (r_ & 7)) * 8)];
      }
#pragma unroll
      for (int n = 0; n < 4; ++n) {
        const int r_ = 64 * wc + 16 * n + lo;
        bfv[n] = *(const bf16x8*)&Bs[r_ * 64 + (((kk * 4 + lg) ^ (r_ & 7)) * 8)];
      }
#pragma unroll
      for (int m = 0; m < 4; ++m)
#pragma unroll
        for (int n = 0; n < 4; ++n)
          acc[m][n] = MFMA16(af[m], bfv[n], acc[m][n]);
    }
    __syncthreads();
  }

  // ---- epilogues (block-uniform mode/segment) ----
  const bool vt_tr = (mode == 0 && n0 >= 2 * D_) || (mode == 1 && n0 >= D_);
  if (vt_tr) {
    // all 64 acc values of this block are vT (+vcache for mode0) outputs.
    unsigned* tr = (unsigned*)shraw;  // [128 c-rows][64 dwords], chunk-XOR swz
    const int b = m0 >> 10;
#pragma unroll
    for (int m = 0; m < 4; ++m)
#pragma unroll
      for (int n = 0; n < 4; ++n) {
        const int cc = 64 * wc + 16 * n + lo;          // tile col (dh axis)
        const int rr0 = 32 * wr + 8 * m + 2 * lg;      // dword row-pair idx
        tr[cc * 64 + ((((rr0 >> 2)) ^ (cc & 15)) << 2) + (rr0 & 3)] =
            pkbf(acc[m][n][0], acc[m][n][1]);
        const int rr1 = rr0 + 1;
        tr[cc * 64 + ((((rr1 >> 2)) ^ (cc & 15)) << 2) + (rr1 & 3)] =
            pkbf(acc[m][n][2], acc[m][n][3]);
        if (mode == 0) {
          const int gc = n0 + cc;
          const int dh = gc & 63, hh = (gc >> 6) & 15;
          const long bh = (long)(b * H_ + hh);
#pragma unroll
          for (int r = 0; r < 4; ++r) {
            const int i = (m0 & 1023) + 64 * wr + 16 * m + 4 * lg + r;
            g.vcache[(bh * MEM_ + i) * DH_ + dh] = acc[m][n][r];
          }
        }
      }
    __syncthreads();
#pragma unroll
    for (int q = 0; q < 8; ++q) {
      const int idx = tid + q * 256;   // 2048 chunks = 128 c x 16 ch
      const int c2 = idx >> 4, ch = idx & 15;
      const uint4 d = *(const uint4*)&tr[c2 * 64 + ((ch ^ (c2 & 15)) << 2)];
      const int gc = n0 + c2;
      const int dh = gc & 63, hh = (gc >> 6) & 15;
      const long bh = (long)(b * H_ + hh);
      const long j = (mode == 0 ? MEM_ : 0) + (m0 & 1023) + ch * 8;
      *(uint4*)&g.vT[(bh * DH_ + dh) * KLEN_ + j] = d;
    }
  } else if (mode == 0) {
#pragma unroll
    for (int m = 0; m < 4; ++m)
#pragma unroll
      for (int n = 0; n < 4; ++n)
#pragma unroll
        for (int r = 0; r < 4; ++r) {
          const float v = acc[m][n][r];
          const int gr = m0 + 64 * wr + 16 * m + lg * 4 + r;
          const int gc = n0 + 64 * wc + 16 * n + lo;
          const int b = gr >> 10, i = gr & 1023;
          const int seg = gc >> 10, c = gc & 1023;
          const int hh = c >> 6, dh = c & 63;
          const long bh = (long)(b * H_ + hh);
          if (seg == 0) {
            const long idx = (bh * Q_ + i) * DH_ + dh;
            g.qw[idx] = f2bf((v + g.rwb[c]) * QSCALE);
            g.qr[idx] = f2bf((v + g.rrb[c]) * QSCALE);
          } else {  // seg == 1 (seg2 handled by vt_tr)
            g.kall[(bh * KLEN_ + MEM_ + i) * DH_ + dh] = f2bf(v);
            g.kcache[(bh * MEM_ + i) * DH_ + dh] = v;
          }
        }
  } else if (mode == 1) {
#pragma unroll
    for (int m = 0; m < 4; ++m)
#pragma unroll
      for (int n = 0; n < 4; ++n)
#pragma unroll
        for (int r = 0; r < 4; ++r) {
          const float v = acc[m][n][r];
          const int gr = m0 + 64 * wr + 16 * m + lg * 4 + r;
          const int gc = n0 + 64 * wc + 16 * n + lo;
          const int b = gr >> 10, i = gr & 1023;
          const int c = gc & 1023;
          const int hh = c >> 6, dh = c & 63;
          const long bh = (long)(b * H_ + hh);
          g.kall[(bh * KLEN_ + i) * DH_ + dh] = f2bf(v);
        }
  } else if (mode == 2) {
#pragma unroll
    for (int m = 0; m < 4; ++m)
#pragma unroll
      for (int n = 0; n < 4; ++n)
#pragma unroll
        for (int r = 0; r < 4; ++r) {
          const float v = acc[m][n][r];
          const int gr = m0 + 64 * wr + 16 * m + lg * 4 + r;
          const int gc = n0 + 64 * wc + 16 * n + lo;
          const int hh = gc >> 6, dh = gc & 63;
          g.rhead[((long)hh * KLEN_ + gr) * DH_ + dh] = f2bf(v);
        }
  } else {
#pragma unroll
    for (int m = 0; m < 4; ++m)
#pragma unroll
      for (int n = 0; n < 4; ++n)
#pragma unroll
        for (int r = 0; r < 4; ++r) {
          const int gr = m0 + 64 * wr + 16 * m + lg * 4 + r;
          const int gc = n0 + 64 * wc + 16 * n + lo;
          g.fout[(long)gr * D_ + gc] = acc[m][n][r];
        }
  }
}

// ---------------- fused attention: swapped-operand S^T form (R11) ----------
// po output now bf16 (packed pkbf stores) -- halves partial-O traffic.
__global__ __launch_bounds__(256) void attn_kernel(
    const bf16* __restrict__ qw, const bf16* __restrict__ qr,
    const bf16* __restrict__ kall, const bf16* __restrict__ vT,
    const bf16* __restrict__ rhead, bf16* __restrict__ po,
    float2* __restrict__ pml) {
  __shared__ bf16 Kt[64 * 64];
  __shared__ bf16 Vt[64 * 64];
  __shared__ bf16 Rt[128 * 64];
  __shared__ bf16 Sd[4][16][86];  // [wave][i-row][band col], stride 86
  __shared__ bf16 Ps[4][16][72];  // [wave][i-row][j col], stride 72
  const int hw = blockIdx.x;
  const int L = ((hw & 7) << 8) | (hw >> 3);
  const int xb = L & 15;
  const int h = (L >> 4) & 15;
  const int js = (L >> 8) & 1;
  const int b = L >> 9;
  const int tid = threadIdx.x;
  const int wid = tid >> 6, lane = tid & 63;
  const int lo = lane & 15, lg = lane >> 4;
  const int I0 = xb * 64;
  const int i0 = I0 + wid * 16;
  const long bh = (long)(b * H_ + h);
  const bf16* rh = rhead + (long)h * KLEN_ * DH_;
  const bf16* kbase = kall + bh * KLEN_ * DH_;
  const bf16* vbase = vT + bh * DH_ * KLEN_;

  const bf16x8 aq0 = *(const bf16x8*)&qw[(bh * Q_ + i0 + lo) * DH_ + lg * 8];
  const bf16x8 aq1 = *(const bf16x8*)&qw[(bh * Q_ + i0 + lo) * DH_ + 32 + lg * 8];
  const bf16x8 ar0 = *(const bf16x8*)&qr[(bh * Q_ + i0 + lo) * DH_ + lg * 8];
  const bf16x8 ar1 = *(const bf16x8*)&qr[(bh * Q_ + i0 + lo) * DH_ + 32 + lg * 8];

  f32x4 o[4] = {};
  float mrun = -1e30f, lrun = 0.f;  // lane-local: one q-row per lane

  const int jbeg = js << 10, jend = jbeg + (KLEN_ / NSPLIT);
  for (int j0 = jbeg; j0 < jend; j0 += 64) {
    const int d0 = j0 - I0 - 63;  // Rt[row] = rhead[m(d0+row)]
#pragma unroll
    for (int ss = 0; ss < 2; ++ss) {
      const int c = tid + ss * 256;
      const int row = c >> 3;
      const int gch = (c & 7) ^ (row & 7);
      GLDS(kbase + (long)(j0 + row) * DH_ + gch * 8, &Kt[c * 8]);
    }
#pragma unroll
    for (int ss = 0; ss < 2; ++ss) {
      const int c = tid + ss * 256;
      const int row = c >> 3;
      const int gch = (c & 7) ^ (row & 7);
      GLDS(vbase + (long)row * KLEN_ + j0 + gch * 8, &Vt[c * 8]);
    }
#pragma unroll
    for (int ss = 0; ss < 4; ++ss) {
      const int c = tid + ss * 256;
      const int row = c >> 3;
      const int dcol = d0 + row;
      int m = dcol + ((dcol >= 1026) ? -1026 : 1023);
      m = max(0, min(m, KLEN_ - 1));
      const int gch = (c & 7) ^ (row & 7);
      GLDS(rh + (long)m * DH_ + gch * 8, &Rt[c * 8]);
    }
    __syncthreads();

    // ---- QK^T swapped: s[t][r] = S[i=i0+lo][j=j0+16t+4lg+r] ----
    f32x4 s[4];
#pragma unroll
    for (int t = 0; t < 4; ++t) {
      const bf16x8 kb0 = *(const bf16x8*)&Kt[swz(16 * t + lo, lg)];
      const bf16x8 kb1 = *(const bf16x8*)&Kt[swz(16 * t + lo, lg + 4)];
      f32x4 z = {};
      z = MFMA16(kb0, aq0, z);
      z = MFMA16(kb1, aq1, z);
      s[t] = z;
    }
    // ---- BD swapped: D[c][i]; lane holds c=crow0+16t+4lg+r, i=i0+lo ----
    const int crow0 = 48 - 16 * wid;
#pragma unroll
    for (int t = 0; t < 5; ++t) {
      const int dtb = d0 + crow0 + 16 * t;
      const bool need1 = (dtb <= 1024);
      const bool need2 = (dtb + 15 >= 1026);
      const int c = crow0 + 16 * t + lo;
      const bf16x8 rb0 = *(const bf16x8*)&Rt[swz(c, lg)];
      const bf16x8 rb1 = *(const bf16x8*)&Rt[swz(c, lg + 4)];
      f32x4 z1 = {}, z2 = {};
      if (need1) { z1 = MFMA16(rb0, ar0, z1); z1 = MFMA16(rb1, ar1, z1); }
      if (need2) {
        const int rs = min(i0 + 1 + lo, Q_ - 1);
        const bf16x8 as0 = *(const bf16x8*)&qr[(bh * Q_ + rs) * DH_ + lg * 8];
        const bf16x8 as1 = *(const bf16x8*)&qr[(bh * Q_ + rs) * DH_ + 32 + lg * 8];
        z2 = MFMA16(rb0, as0, z2);
        z2 = MFMA16(rb1, as1, z2);
      }
      float v0, v1, v2, v3;
      {
        const int dlt0 = dtb + 4 * lg;
        v0 = (dlt0 + 0 >= 1026) ? z2[0] : z1[0]; if (dlt0 + 0 == 1025) v0 = 0.f;
        v1 = (dlt0 + 1 >= 1026) ? z2[1] : z1[1]; if (dlt0 + 1 == 1025) v1 = 0.f;
        v2 = (dlt0 + 2 >= 1026) ? z2[2] : z1[2]; if (dlt0 + 2 == 1025) v2 = 0.f;
        v3 = (dlt0 + 3 >= 1026) ? z2[3] : z1[3]; if (dlt0 + 3 == 1025) v3 = 0.f;
      }
      *(unsigned*)&Sd[wid][lo][16 * t + 4 * lg]     = pkbf(v0, v1);
      *(unsigned*)&Sd[wid][lo][16 * t + 4 * lg + 2] = pkbf(v2, v3);
    }
    // ---- softmax: row i=i0+lo lane-local; tree reduce + 2 shfl ----
#pragma unroll
    for (int t = 0; t < 4; ++t)
#pragma unroll
      for (int r = 0; r < 4; ++r)
        s[t][r] += bf2f(Sd[wid][lo][16 * t + 4 * lg + r - lo + 15]);
    const float m0t = fmaxf(fmaxf(s[0][0], s[0][1]), fmaxf(s[0][2], s[0][3]));
    const float m1t = fmaxf(fmaxf(s[1][0], s[1][1]), fmaxf(s[1][2], s[1][3]));
    const float m2t = fmaxf(fmaxf(s[2][0], s[2][1]), fmaxf(s[2][2], s[2][3]));
    const float m3t = fmaxf(fmaxf(s[3][0], s[3][1]), fmaxf(s[3][2], s[3][3]));
    float mt = fmaxf(fmaxf(m0t, m1t), fmaxf(m2t, m3t));
    mt = fmaxf(mt, __shfl_xor(mt, 16));
    mt = fmaxf(mt, __shfl_xor(mt, 32));
    const float mnew = fmaxf(mrun, mt);
    const float scale = ex2(mrun - mnew);
#pragma unroll
    for (int t = 0; t < 4; ++t)
#pragma unroll
      for (int r = 0; r < 4; ++r)
        s[t][r] = ex2(s[t][r] - mnew);
    const float r0t = (s[0][0] + s[0][1]) + (s[0][2] + s[0][3]);
    const float r1t = (s[1][0] + s[1][1]) + (s[1][2] + s[1][3]);
    const float r2t = (s[2][0] + s[2][1]) + (s[2][2] + s[2][3]);
    const float r3t = (s[3][0] + s[3][1]) + (s[3][2] + s[3][3]);
    float rsum = (r0t + r1t) + (r2t + r3t);
    rsum += __shfl_xor(rsum, 16);
    rsum += __shfl_xor(rsum, 32);
    lrun = lrun * scale + rsum;
    mrun = mnew;
#pragma unroll
    for (int u = 0; u < 4; ++u)
#pragma unroll
      for (int r = 0; r < 4; ++r) o[u][r] *= scale;
    // ---- P pack -> Ps (plain stride-72), read as B-frag ----
#pragma unroll
    for (int t = 0; t < 4; ++t) {
      *(unsigned*)&Ps[wid][lo][16 * t + 4 * lg]     = pkbf(s[t][0], s[t][1]);
      *(unsigned*)&Ps[wid][lo][16 * t + 4 * lg + 2] = pkbf(s[t][2], s[t][3]);
    }
    const bf16x8 pa0 = *(const bf16x8*)&Ps[wid][lo][8 * lg];
    const bf16x8 pa1 = *(const bf16x8*)&Ps[wid][lo][32 + 8 * lg];
    // ---- PV swapped: o[u] accumulates O^T[d=16u+4lg+r][i=i0+lo] ----
#pragma unroll
    for (int u = 0; u < 4; ++u) {
      const bf16x8 vb0 = *(const bf16x8*)&Vt[swz(16 * u + lo, lg)];
      const bf16x8 vb1 = *(const bf16x8*)&Vt[swz(16 * u + lo, lg + 4)];
      o[u] = MFMA16(vb0, pa0, o[u]);
      o[u] = MFMA16(vb1, pa1, o[u]);
    }
    __syncthreads();
  }
  // ---- partial outputs: bf16 packed (8B stores) ----
  const int i = i0 + lo;
  const long obase = (((long)(bh * Q_ + i)) * NSPLIT + js) * DH_;
#pragma unroll
  for (int u = 0; u < 4; ++u) {
    uint2 d;
    d.x = pkbf(o[u][0], o[u][1]);
    d.y = pkbf(o[u][2], o[u][3]);
    *(uint2*)&po[obase + 16 * u + 4 * lg] = d;
  }
  if (lg == 0)
    pml[((long)(bh * Q_ + i)) * NSPLIT + js] = make_float2(mrun, lrun);
}

// ---------------- combine partial softmax halves (log2 domain, bf16 po) ----
__global__ __launch_bounds__(256) void combine_kernel(
    const bf16* __restrict__ po, const float2* __restrict__ pml,
    bf16* __restrict__ attnv) {
  const long gid = (long)blockIdx.x * 256 + threadIdx.x;  // B*H*Q*DH
  const int col = gid & 63;
  const long row = gid >> 6;  // bh*Q + i
  const float2 ml0 = pml[row * NSPLIT];
  const float2 ml1 = pml[row * NSPLIT + 1];
  const float m = fmaxf(ml0.x, ml1.x);
  const float w0 = ex2(ml0.x - m), w1 = ex2(ml1.x - m);
  const float num = bf2f(po[(row * NSPLIT) * DH_ + col]) * w0 +
                    bf2f(po[(row * NSPLIT + 1) * DH_ + col]) * w1;
  const float den = ml0.y * w0 + ml1.y * w1;
  const int b = (int)(row >> 14);
  const int h = (int)(row >> 10) & 15;
  const int i = (int)row & 1023;
  attnv[((long)(b * Q_ + i)) * D_ + h * DH_ + col] = f2bf(num / den);
}

// ---------------- host ----------------
extern "C" void kernel_launch(void* const* d_in, const int* in_sizes, int n_in,
                              void* d_out, int out_size, void* d_ws, size_t ws_size,
                              hipStream_t stream) {
  (void)in_sizes; (void)n_in; (void)out_size; (void)ws_size;
  const float* h_in  = (const float*)d_in[0];
  const float* mem_in= (const float*)d_in[1];
  const float* r_in  = (const float*)d_in[2];
  const float* Wq = (const float*)d_in[3];
  const float* Wk = (const float*)d_in[4];
  const float* Wv = (const float*)d_in[5];
  const float* Wr = (const float*)d_in[6];
  const float* Wo = (const float*)d_in[7];
  const float* rwb = (const float*)d_in[8];
  const float* rrb = (const float*)d_in[9];

  float* out = (float*)d_out;
  float* kcache = out + (long)B_ * Q_ * D_;
  float* vcache = kcache + (long)B_ * H_ * MEM_ * DH_;

  char* w = (char*)d_ws;
  auto alloc = [&](size_t bytes) {
    char* p = w;
    w += (bytes + 255) & ~(size_t)255;
    return p;
  };
  bf16* h_bf   = (bf16*)alloc((size_t)B_ * Q_ * D_ * 2);
  bf16* mem_bf = (bf16*)alloc((size_t)B_ * MEM_ * D_ * 2);
  bf16* r_bf   = (bf16*)alloc((size_t)KLEN_ * D_ * 2);
  bf16* Wqt = (bf16*)alloc((size_t)D_ * D_ * 2);   // Wqt/Wkt/Wvt contiguous:
  bf16* Wkt = (bf16*)alloc((size_t)D_ * D_ * 2);   // HQKV gemm spans N=3072
  bf16* Wvt = (bf16*)alloc((size_t)D_ * D_ * 2);
  bf16* Wrt = (bf16*)alloc((size_t)D_ * D_ * 2);
  bf16* Wot = (bf16*)alloc((size_t)D_ * D_ * 2);
  bf16* qw    = (bf16*)alloc((size_t)B_ * H_ * Q_ * DH_ * 2);
  bf16* qr    = (bf16*)alloc((size_t)B_ * H_ * Q_ * DH_ * 2);
  bf16* kall  = (bf16*)alloc((size_t)B_ * H_ * KLEN_ * DH_ * 2);
  bf16* vT    = (bf16*)alloc((size_t)B_ * H_ * KLEN_ * DH_ * 2);
  bf16* rhead = (bf16*)alloc((size_t)H_ * KLEN_ * DH_ * 2);
  bf16* attnv = (bf16*)alloc((size_t)B_ * Q_ * D_ * 2);
  bf16* po    = (bf16*)alloc((size_t)B_ * H_ * Q_ * NSPLIT * DH_ * 2);
  float2* pml = (float2*)alloc((size_t)B_ * H_ * Q_ * NSPLIT * 8);

  // 1. f32 -> bf16 conversions
  CvtArgs ca;
  ca.src[0] = h_in;   ca.dst[0] = h_bf;   ca.n4[0] = B_ * Q_ * D_ / 4;
  ca.src[1] = mem_in; ca.dst[1] = mem_bf; ca.n4[1] = B_ * MEM_ * D_ / 4;
  ca.src[2] = r_in;   ca.dst[2] = r_bf;   ca.n4[2] = KLEN_ * D_ / 4;
  cvt_kernel<<<dim3((B_ * Q_ * D_ / 4 + 255) / 256, 1, 3), 256, 0, stream>>>(ca);

  // 2. weight transposes
  TpArgs ta;
  ta.w[0] = Wq; ta.o[0] = Wqt;
  ta.w[1] = Wk; ta.o[1] = Wkt;
  ta.w[2] = Wv; ta.o[2] = Wvt;
  ta.w[3] = Wr; ta.o[3] = Wrt;
  ta.w[4] = Wo; ta.o[4] = Wot;
  tp_kernel<<<dim3(32, 32, 5), dim3(32, 8), 0, stream>>>(ta);

  GemmArgs g{};
  g.h_bf = h_bf; g.mem_bf = mem_bf; g.r_bf = r_bf; g.attnv = attnv;
  g.Wqt = Wqt; g.Wkt = Wkt; g.Wrt = Wrt; g.Wot = Wot;
  g.qw = qw; g.qr = qr; g.kall = kall; g.vT = vT; g.rhead = rhead;
  g.kcache = kcache; g.vcache = vcache; g.fout = out; g.rwb = rwb; g.rrb = rrb;

  // 3. fused projections: {h@[Wq|Wk|Wv] (768 wgs), mem@[Wk|Wv] (512), r@Wr (128)}
  gemm_fused<<<dim3(1408), 256, 0, stream>>>(g, 0);

  // 4. fused attention (KV-split, XCD-swizzled, swapped-operand) + combine
  attn_kernel<<<dim3(Q_ / 64 * H_ * B_ * NSPLIT), 256, 0, stream>>>(
      qw, qr, kall, vT, rhead, po, pml);
  combine_kernel<<<dim3(B_ * H_ * Q_ * DH_ / 256), 256, 0, stream>>>(po, pml, attnv);

  // 5. out = attnv @ Wo  (M=4096, N=1024, K=1024)
  gemm_fused<<<dim3(256), 256, 0, stream>>>(g, 1);
}